// Round 2
// baseline (3680.215 us; speedup 1.0000x reference)
//
#include <hip/hip_runtime.h>
#include <hip/hip_bf16.h>

#define N_NODESC 100000
#define N_EDGESC 200000
#define BG 2048
#define NDIM 64
#define EDIM 16
#define CH 12800   // GINE2 node chunk (7 full chunks + 10400 tail)

static __device__ __forceinline__ float bn_inv() { return 0.9999950000374997f; }

// ---------------- generic zero fill (float4) ---------------------------------
__global__ void zero_f4(float4* __restrict__ p, int n4) {
    int i = blockIdx.x * 256 + threadIdx.x;
    if (i < n4) p[i] = make_float4(0.f, 0.f, 0.f, 0.f);
}

__global__ void zero_out(float* __restrict__ p, int n) {
    int i = blockIdx.x * 256 + threadIdx.x;
    if (i < n) p[i] = 0.f;
}

// ---------------- GINE1: per-edge message + scatter (64 dims, 1 wave/edge) ---
__global__ void gine1_msg(const float* __restrict__ x, const int* __restrict__ src,
                          const int* __restrict__ dst, const float* __restrict__ ea,
                          const float* __restrict__ e1W, const float* __restrict__ e1b,
                          float* __restrict__ aggr) {
    int e = blockIdx.x * 4 + (threadIdx.x >> 6);
    int lane = threadIdx.x & 63;
    if (e >= N_EDGESC) return;
    int s = src[e], d = dst[e];
    float acc = e1b[lane];
    const float* eap = ea + (size_t)e * EDIM;
#pragma unroll
    for (int k = 0; k < EDIM; k++) acc = fmaf(eap[k], e1W[k * NDIM + lane], acc);
    float m = x[(size_t)s * NDIM + lane] + acc;
    atomicAdd(&aggr[(size_t)d * NDIM + lane], fmaxf(m, 0.f));
}

// ---------------- GEMM1: h = relu(bn1((x+aggr)@W + b)) -> bf16 ---------------
__global__ void gemm1(const float* __restrict__ x, const float* __restrict__ aggr,
                      const float* __restrict__ W, const float* __restrict__ b,
                      const float* __restrict__ g, const float* __restrict__ bb,
                      __hip_bfloat16* __restrict__ h) {
    __shared__ float arow[8 * 64];
    int r0 = blockIdx.x * 8;
    int tid = threadIdx.x;
    if (tid < 128) {
        const float4* x4 = (const float4*)(x + (size_t)r0 * 64);
        const float4* a4 = (const float4*)(aggr + (size_t)r0 * 64);
        float4 xv = x4[tid], av = a4[tid];
        ((float4*)arow)[tid] = make_float4(xv.x + av.x, xv.y + av.y, xv.z + av.z, xv.w + av.w);
    }
    __syncthreads();
    int c0 = tid, c1 = tid + 256;
    float acc0[8] = {}, acc1[8] = {};
    const float4* s4 = (const float4*)arow;
    for (int k4 = 0; k4 < 16; k4++) {
        int k = k4 << 2;
        float w00 = W[(k + 0) * 512 + c0], w01 = W[(k + 1) * 512 + c0];
        float w02 = W[(k + 2) * 512 + c0], w03 = W[(k + 3) * 512 + c0];
        float w10 = W[(k + 0) * 512 + c1], w11 = W[(k + 1) * 512 + c1];
        float w12 = W[(k + 2) * 512 + c1], w13 = W[(k + 3) * 512 + c1];
#pragma unroll
        for (int r = 0; r < 8; r++) {
            float4 a = s4[r * 16 + k4];
            acc0[r] = fmaf(a.x, w00, acc0[r]); acc0[r] = fmaf(a.y, w01, acc0[r]);
            acc0[r] = fmaf(a.z, w02, acc0[r]); acc0[r] = fmaf(a.w, w03, acc0[r]);
            acc1[r] = fmaf(a.x, w10, acc1[r]); acc1[r] = fmaf(a.y, w11, acc1[r]);
            acc1[r] = fmaf(a.z, w12, acc1[r]); acc1[r] = fmaf(a.w, w13, acc1[r]);
        }
    }
    float bias0 = b[c0], bias1 = b[c1];
    float g0 = g[c0], g1v = g[c1], bb0 = bb[c0], bb1 = bb[c1];
#pragma unroll
    for (int r = 0; r < 8; r++) {
        int row = r0 + r;
        float v0 = fmaxf(fmaf((acc0[r] + bias0) * bn_inv(), g0, bb0), 0.f);
        float v1 = fmaxf(fmaf((acc1[r] + bias1) * bn_inv(), g1v, bb1), 0.f);
        h[(size_t)row * 512 + c0] = __float2bfloat16(v0);
        h[(size_t)row * 512 + c1] = __float2bfloat16(v1);
    }
}

// ---------------- GINE2 msg, chunked over dst (1 wave/edge) ------------------
__global__ void gine2_msg_chunk(const __hip_bfloat16* __restrict__ h,
                                const int* __restrict__ src, const int* __restrict__ dst,
                                const float* __restrict__ ea, const float* __restrict__ e2W,
                                const float* __restrict__ e2b, float* __restrict__ aggrc,
                                int c0n, int c1n) {
    int e = blockIdx.x * 4 + (threadIdx.x >> 6);
    int lane = threadIdx.x & 63;
    if (e >= N_EDGESC) return;
    int d = dst[e];
    if (d < c0n || d >= c1n) return;
    int s = src[e];
    const float* eap = ea + (size_t)e * EDIM;
    float ev[16];
#pragma unroll
    for (int k = 0; k < 16; k++) ev[k] = eap[k];
    const __hip_bfloat16* hp = h + (size_t)s * 512;
    float* ap = aggrc + (size_t)(d - c0n) * 512;
#pragma unroll
    for (int j = 0; j < 8; j++) {
        int c = lane + j * 64;
        float acc = e2b[c];
#pragma unroll
        for (int k = 0; k < 16; k++) acc = fmaf(ev[k], e2W[k * 512 + c], acc);
        float m = __bfloat162float(hp[c]) + acc;
        atomicAdd(ap + c, fmaxf(m, 0.f));
    }
}

// ---------------- node counts per graph --------------------------------------
__global__ void count_nodes(const int* __restrict__ batch, float* __restrict__ cnt) {
    int i = blockIdx.x * 256 + threadIdx.x;
    if (i < N_NODESC) atomicAdd(&cnt[batch[i]], 1.0f);
}

// ---------------- GEMM2 + pooled epilogue (per node chunk) -------------------
__global__ void gemm2_pool(const __hip_bfloat16* __restrict__ hc, const float* __restrict__ ac,
                           const float* __restrict__ W, const float* __restrict__ b,
                           const float* __restrict__ g, const float* __restrict__ bb,
                           const int* __restrict__ batchc, float* __restrict__ psum) {
    __shared__ float arow[16 * 512];
    int r0 = blockIdx.x * 16;  // relative to chunk base
    int tid = threadIdx.x;
    {
        const __hip_bfloat162* h2 = (const __hip_bfloat162*)(hc + (size_t)r0 * 512);
        const float2* a2 = (const float2*)(ac + (size_t)r0 * 512);
        for (int i = tid; i < 16 * 256; i += 256) {
            __hip_bfloat162 hv = h2[i];
            float2 av = a2[i];
            arow[2 * i] = __bfloat162float(hv.x) + av.x;
            arow[2 * i + 1] = __bfloat162float(hv.y) + av.y;
        }
    }
    __syncthreads();
    int c0 = tid, c1 = tid + 256;
    float acc0[16] = {}, acc1[16] = {};
    const float4* s4 = (const float4*)arow;
    for (int k4 = 0; k4 < 128; k4++) {
        int k = k4 << 2;
        float w00 = W[(k + 0) * 512 + c0], w01 = W[(k + 1) * 512 + c0];
        float w02 = W[(k + 2) * 512 + c0], w03 = W[(k + 3) * 512 + c0];
        float w10 = W[(k + 0) * 512 + c1], w11 = W[(k + 1) * 512 + c1];
        float w12 = W[(k + 2) * 512 + c1], w13 = W[(k + 3) * 512 + c1];
#pragma unroll
        for (int r = 0; r < 16; r++) {
            float4 a = s4[r * 128 + k4];
            acc0[r] = fmaf(a.x, w00, acc0[r]); acc0[r] = fmaf(a.y, w01, acc0[r]);
            acc0[r] = fmaf(a.z, w02, acc0[r]); acc0[r] = fmaf(a.w, w03, acc0[r]);
            acc1[r] = fmaf(a.x, w10, acc1[r]); acc1[r] = fmaf(a.y, w11, acc1[r]);
            acc1[r] = fmaf(a.z, w12, acc1[r]); acc1[r] = fmaf(a.w, w13, acc1[r]);
        }
    }
    float bias0 = b[c0], bias1 = b[c1];
    float g0 = g[c0], g1v = g[c1], bb0 = bb[c0], bb1 = bb[c1];
    for (int r = 0; r < 16; r++) {
        int bi = batchc[r0 + r];
        float v0 = fmaxf(fmaf((acc0[r] + bias0) * bn_inv(), g0, bb0), 0.f);
        float v1 = fmaxf(fmaf((acc1[r] + bias1) * bn_inv(), g1v, bb1), 0.f);
        atomicAdd(&psum[(size_t)bi * 512 + c0], v0);
        atomicAdd(&psum[(size_t)bi * 512 + c1], v1);
    }
}

// ---------------- finalize pool + assemble xn [B,7,512] ----------------------
__global__ void build_xn(const float* __restrict__ psum, const float* __restrict__ cnt,
                         const float* __restrict__ ecfp, const float* __restrict__ topo,
                         const float* __restrict__ maccs, const float* __restrict__ estate,
                         const float* __restrict__ rdkit2d, const float* __restrict__ phar2d,
                         float* __restrict__ xn) {
    int i = blockIdx.x * 256 + threadIdx.x;
    if (i >= BG * 512) return;
    int bidx = i >> 9, c = i & 511;
    float cv = fmaxf(cnt[bidx], 1.0f);
    float* o = xn + (size_t)bidx * 7 * 512;
    o[c] = psum[i] / cv;
    o[512 + c] = ecfp[i];
    o[2 * 512 + c] = topo[i];
    o[3 * 512 + c] = maccs[i];
    o[4 * 512 + c] = estate[i];
    o[5 * 512 + c] = rdkit2d[i];
    o[6 * 512 + c] = phar2d[i];
}

// ---------------- GAT transform GEMM: [M,512]@[512,2048]+bias -> bf16 --------
__global__ void gat_gemm(const float* __restrict__ Ain, const float* __restrict__ W,
                         const float* __restrict__ bias, __hip_bfloat16* __restrict__ Cout) {
    __shared__ float arow[16 * 512];
    int r0 = blockIdx.x * 16;
    int cbase = blockIdx.y * 512;
    int tid = threadIdx.x;
    {
        float4* s4 = (float4*)arow;
        const float4* a4 = (const float4*)(Ain + (size_t)r0 * 512);
        for (int i = tid; i < 16 * 128; i += 256) s4[i] = a4[i];
    }
    __syncthreads();
    int c0 = cbase + tid, c1 = cbase + tid + 256;
    float acc0[16] = {}, acc1[16] = {};
    const float4* s4 = (const float4*)arow;
    for (int k4 = 0; k4 < 128; k4++) {
        int k = k4 << 2;
        float w00 = W[(size_t)(k + 0) * 2048 + c0], w01 = W[(size_t)(k + 1) * 2048 + c0];
        float w02 = W[(size_t)(k + 2) * 2048 + c0], w03 = W[(size_t)(k + 3) * 2048 + c0];
        float w10 = W[(size_t)(k + 0) * 2048 + c1], w11 = W[(size_t)(k + 1) * 2048 + c1];
        float w12 = W[(size_t)(k + 2) * 2048 + c1], w13 = W[(size_t)(k + 3) * 2048 + c1];
#pragma unroll
        for (int r = 0; r < 16; r++) {
            float4 a = s4[r * 128 + k4];
            acc0[r] = fmaf(a.x, w00, acc0[r]); acc0[r] = fmaf(a.y, w01, acc0[r]);
            acc0[r] = fmaf(a.z, w02, acc0[r]); acc0[r] = fmaf(a.w, w03, acc0[r]);
            acc1[r] = fmaf(a.x, w10, acc1[r]); acc1[r] = fmaf(a.y, w11, acc1[r]);
            acc1[r] = fmaf(a.z, w12, acc1[r]); acc1[r] = fmaf(a.w, w13, acc1[r]);
        }
    }
    float b0 = bias[c0], b1 = bias[c1];
#pragma unroll
    for (int r = 0; r < 16; r++) {
        Cout[(size_t)(r0 + r) * 2048 + c0] = __float2bfloat16(acc0[r] + b0);
        Cout[(size_t)(r0 + r) * 2048 + c1] = __float2bfloat16(acc1[r] + b1);
    }
}

// ---------------- GAT attention + aggregate + bn + relu (1 block/graph) ------
__global__ void gat_attn(const __hip_bfloat16* __restrict__ gl, const __hip_bfloat16* __restrict__ gr,
                         const float* __restrict__ att, const float* __restrict__ bias,
                         const float* __restrict__ bng, const float* __restrict__ bnb,
                         float* __restrict__ zout) {
    int b = blockIdx.x;
    int tid = threadIdx.x;
    int wave = tid >> 6, lane = tid & 63;
    __shared__ float logits[13][4];
    __shared__ float alpha[13][4];
    const size_t base = (size_t)b * 7 * 4 * 512;
    // step 1: 52 logits, one wave-reduced dot each
    for (int p = wave; p < 52; p += 4) {
        int e = p >> 2, hh = p & 3;
        int se = (e < 7) ? 0 : (e - 6);
        int de = (e < 6) ? (e + 1) : ((e == 6) ? 0 : (e - 6));
        const __hip_bfloat16* glp = gl + base + (size_t)(se * 4 + hh) * 512;
        const __hip_bfloat16* grp = gr + base + (size_t)(de * 4 + hh) * 512;
        const float* ap = att + hh * 512;
        float s = 0.f;
#pragma unroll
        for (int j = 0; j < 8; j++) {
            int c = lane + j * 64;
            float v = __bfloat162float(glp[c]) + __bfloat162float(grp[c]);
            v = (v >= 0.f) ? v : 0.2f * v;
            s = fmaf(v, ap[c], s);
        }
#pragma unroll
        for (int off = 32; off; off >>= 1) s += __shfl_down(s, off);
        if (lane == 0) logits[e][hh] = s;
    }
    __syncthreads();
    // step 2: segment softmax. dst 0 has 1 in-edge (e=6); dst n>=1 has {n-1, 6+n}
    if (tid < 24) {
        int n = 1 + (tid >> 2), hh = tid & 3;
        float la = logits[n - 1][hh], lb = logits[6 + n][hh];
        float m = fmaxf(la, lb);
        float ea = __expf(la - m), eb = __expf(lb - m);
        float inv = 1.f / (ea + eb);
        alpha[n - 1][hh] = ea * inv;
        alpha[6 + n][hh] = eb * inv;
    } else if (tid < 28) {
        alpha[6][tid & 3] = 1.f;
    }
    __syncthreads();
    // step 3: z[n,c] = mean_h sum_{in-edges} alpha*gl[src] + bias; bn+relu
    for (int i = tid; i < 7 * 512; i += 256) {
        int n = i >> 9, c = i & 511;
        float v = 0.f;
        if (n == 0) {
#pragma unroll
            for (int hh = 0; hh < 4; hh++)
                v = fmaf(alpha[6][hh], __bfloat162float(gl[base + (size_t)hh * 512 + c]), v);
        } else {
#pragma unroll
            for (int hh = 0; hh < 4; hh++) {
                v = fmaf(alpha[n - 1][hh], __bfloat162float(gl[base + (size_t)hh * 512 + c]), v);
                v = fmaf(alpha[6 + n][hh],
                         __bfloat162float(gl[base + (size_t)(n * 4 + hh) * 512 + c]), v);
            }
        }
        v = fmaf(v, 0.25f, bias[c]);
        v = fmaf(v * bn_inv(), bng[c], bnb[c]);
        zout[(size_t)b * 7 * 512 + i] = fmaxf(v, 0.f);
    }
}

// ---------------- final fc: out[b] = z2[b,0,:]@fc_W + fc_b -------------------
__global__ void final_fc(const float* __restrict__ z, const float* __restrict__ fcW,
                         const float* __restrict__ fcb, float* __restrict__ out) {
    int b = blockIdx.x * 4 + (threadIdx.x >> 6);
    int lane = threadIdx.x & 63;
    if (b >= BG) return;
    const float* row = z + (size_t)b * 7 * 512;
    float s = 0.f;
#pragma unroll
    for (int j = 0; j < 8; j++) s = fmaf(row[lane + j * 64], fcW[lane + j * 64], s);
#pragma unroll
    for (int off = 32; off; off >>= 1) s += __shfl_down(s, off);
    if (lane == 0) out[b] = s + fcb[0];
}

extern "C" void kernel_launch(void* const* d_in, const int* in_sizes, int n_in,
                              void* d_out, int out_size, void* d_ws, size_t ws_size,
                              hipStream_t stream) {
    const float* x = (const float*)d_in[0];
    const int* eidx = (const int*)d_in[1];
    const float* eattr = (const float*)d_in[2];
    const int* batch = (const int*)d_in[3];
    const float* ecfp = (const float*)d_in[4];
    const float* topo = (const float*)d_in[5];
    const float* maccs = (const float*)d_in[6];
    const float* estate = (const float*)d_in[7];
    const float* rdkit2d = (const float*)d_in[8];
    const float* phar2d = (const float*)d_in[9];
    const float* g1_W = (const float*)d_in[10];
    const float* g1_b = (const float*)d_in[11];
    const float* e1_W = (const float*)d_in[12];
    const float* e1_b = (const float*)d_in[13];
    const float* bn1_g = (const float*)d_in[14];
    const float* bn1_b = (const float*)d_in[15];
    const float* g2_W = (const float*)d_in[16];
    const float* g2_b = (const float*)d_in[17];
    const float* e2_W = (const float*)d_in[18];
    const float* e2_b = (const float*)d_in[19];
    const float* bn2_g = (const float*)d_in[20];
    const float* bn2_b = (const float*)d_in[21];
    const float* gat1_Wl = (const float*)d_in[22];
    const float* gat1_bl = (const float*)d_in[23];
    const float* gat1_Wr = (const float*)d_in[24];
    const float* gat1_br = (const float*)d_in[25];
    const float* gat1_att = (const float*)d_in[26];
    const float* gat1_bias = (const float*)d_in[27];
    const float* bn3_g = (const float*)d_in[28];
    const float* bn3_b = (const float*)d_in[29];
    const float* gat2_Wl = (const float*)d_in[30];
    const float* gat2_bl = (const float*)d_in[31];
    const float* gat2_Wr = (const float*)d_in[32];
    const float* gat2_br = (const float*)d_in[33];
    const float* gat2_att = (const float*)d_in[34];
    const float* gat2_bias = (const float*)d_in[35];
    const float* bn4_g = (const float*)d_in[36];
    const float* bn4_b = (const float*)d_in[37];
    const float* fc_W = (const float*)d_in[38];
    const float* fc_b = (const float*)d_in[39];
    float* out = (float*)d_out;

    // ---- workspace layout (byte offsets, total 194,682,880 B) ----
    // [0,          102,400,000): h bf16 (N x 512)   | later: gl bf16 (58.7MB) + z1 f32 (29.4MB)
    // [102.4M,    +58,720,256): aggr1 f32 / aggr2-chunk f32 | later: gr bf16
    // [161.1M,    +29,360,128): xn f32              | later: z2 f32
    // [190.5M,    + 4,194,304): psum f32
    // [194.67M,   +     8,192): cnt f32
    const size_t NEEDED = 102400000ull + 58720256ull + 29360128ull + 4194304ull + 8192ull;
    if (ws_size < NEEDED) {  // diagnostic fallback: readable absmax fail, not a fault
        zero_out<<<(BG + 255) / 256, 256, 0, stream>>>(out, BG);
        return;
    }
    char* w = (char*)d_ws;
    __hip_bfloat16* H = (__hip_bfloat16*)w;
    __hip_bfloat16* GL = (__hip_bfloat16*)w;
    float* Z1 = (float*)(w + 58720256);
    float* AGG = (float*)(w + 102400000);
    __hip_bfloat16* GR = (__hip_bfloat16*)(w + 102400000);
    float* XN = (float*)(w + 102400000 + 58720256);
    float* Z2 = XN;
    float* PS = (float*)(w + 102400000 + 58720256 + 29360128);
    float* PC = (float*)(w + 102400000 + 58720256 + 29360128 + 4194304);

    const int* src = eidx;
    const int* dst = eidx + N_EDGESC;

    // ---- GINE1 ----
    zero_f4<<<(N_NODESC * NDIM / 4 + 255) / 256, 256, 0, stream>>>((float4*)AGG,
                                                                   N_NODESC * NDIM / 4);
    zero_f4<<<(BG * 512 / 4 + 255) / 256, 256, 0, stream>>>((float4*)PS, BG * 512 / 4);
    zero_f4<<<(BG / 4 + 255) / 256, 256, 0, stream>>>((float4*)PC, BG / 4);
    gine1_msg<<<N_EDGESC / 4, 256, 0, stream>>>(x, src, dst, eattr, e1_W, e1_b, AGG);
    gemm1<<<N_NODESC / 8, 256, 0, stream>>>(x, AGG, g1_W, g1_b, bn1_g, bn1_b, H);
    count_nodes<<<(N_NODESC + 255) / 256, 256, 0, stream>>>(batch, PC);

    // ---- GINE2, chunked over dst nodes ----
    for (int c0n = 0; c0n < N_NODESC; c0n += CH) {
        int c1n = c0n + CH < N_NODESC ? c0n + CH : N_NODESC;
        int rows = c1n - c0n;
        int n4 = rows * 512 / 4;
        zero_f4<<<(n4 + 255) / 256, 256, 0, stream>>>((float4*)AGG, n4);
        gine2_msg_chunk<<<N_EDGESC / 4, 256, 0, stream>>>(H, src, dst, eattr, e2_W, e2_b,
                                                          AGG, c0n, c1n);
        gemm2_pool<<<rows / 16, 256, 0, stream>>>(H + (size_t)c0n * 512, AGG, g2_W, g2_b,
                                                  bn2_g, bn2_b, batch + c0n, PS);
    }

    // ---- pool -> xn ----
    build_xn<<<(BG * 512) / 256, 256, 0, stream>>>(PS, PC, ecfp, topo, maccs, estate,
                                                   rdkit2d, phar2d, XN);
    // ---- GAT layer 1 ----
    dim3 ggrid(BG * 7 / 16, 4);
    gat_gemm<<<ggrid, 256, 0, stream>>>(XN, gat1_Wl, gat1_bl, GL);
    gat_gemm<<<ggrid, 256, 0, stream>>>(XN, gat1_Wr, gat1_br, GR);
    gat_attn<<<BG, 256, 0, stream>>>(GL, GR, gat1_att, gat1_bias, bn3_g, bn3_b, Z1);
    // ---- GAT layer 2 ----
    gat_gemm<<<ggrid, 256, 0, stream>>>(Z1, gat2_Wl, gat2_bl, GL);
    gat_gemm<<<ggrid, 256, 0, stream>>>(Z1, gat2_Wr, gat2_br, GR);
    gat_attn<<<BG, 256, 0, stream>>>(GL, GR, gat2_att, gat2_bias, bn4_g, bn4_b, Z2);
    // ---- final fc ----
    final_fc<<<BG / 4, 256, 0, stream>>>(Z2, fc_W, fc_b, out);
}

// Round 3
// 1600.509 us; speedup vs baseline: 2.2994x; 2.2994x over previous
//
#include <hip/hip_runtime.h>
#include <hip/hip_bf16.h>

#define N_NODESC 100000
#define N_EDGESC 200000
#define BG 2048
#define NDIM 64
#define EDIM 16
#define CH 12800   // GINE2 node chunk

typedef __bf16 bf16x8 __attribute__((ext_vector_type(8)));
typedef float f32x4 __attribute__((ext_vector_type(4)));

static __device__ __forceinline__ float bn_inv() { return 0.9999950000374997f; }

// ---------------- generic zero fill (float4) ---------------------------------
__global__ void zero_f4(float4* __restrict__ p, int n4) {
    int i = blockIdx.x * 256 + threadIdx.x;
    if (i < n4) p[i] = make_float4(0.f, 0.f, 0.f, 0.f);
}

__global__ void zero_out(float* __restrict__ p, int n) {
    int i = blockIdx.x * 256 + threadIdx.x;
    if (i < n) p[i] = 0.f;
}

// ---------------- W [K][N] f32 -> Wt hi/lo bf16 [N][K] ------------------------
__global__ void transpose_wt(const float* __restrict__ W, __hip_bfloat16* __restrict__ hi,
                             __hip_bfloat16* __restrict__ lo, int K, int N) {
    __shared__ float t[64][65];
    int k0 = blockIdx.x * 64, n0 = blockIdx.y * 64;
    int tid = threadIdx.x;
    int tx = tid & 63, ty = tid >> 6;
    for (int r = ty; r < 64; r += 4) t[r][tx] = W[(size_t)(k0 + r) * N + n0 + tx];
    __syncthreads();
    for (int r = ty; r < 64; r += 4) {
        float w = t[tx][r];
        __hip_bfloat16 h = __float2bfloat16(w);
        float resid = w - __bfloat162float(h);
        size_t o = (size_t)(n0 + r) * K + k0 + tx;
        hi[o] = h;
        lo[o] = __float2bfloat16(resid);
    }
}

// ---------------- MFMA GEMM: C[M,N] = A[M,K](bf16) @ (Bhi+Blo)^T[N,K] ---------
// 128x128 tile, 256 threads (4 waves, 2x2), 4x4 16x16x32 accumulators per wave.
// MODE 0: C = acc + bias[n]              -> bf16 Cout [M,N]
// MODE 1: C = relu(bn(acc + bias))       -> bf16 Cout [M,512]
// MODE 2: C = relu(bn(acc + bias)), atomicAdd psum[batch[m]*512 + n]
#define ASTR 40
template <int MODE>
__global__ __launch_bounds__(256, 2) void mfma_gemm(
    const __hip_bfloat16* __restrict__ A, const __hip_bfloat16* __restrict__ Bhi,
    const __hip_bfloat16* __restrict__ Blo, int M, int K, int N,
    const float* __restrict__ bias, const float* __restrict__ bng,
    const float* __restrict__ bnb, const int* __restrict__ batch,
    float* __restrict__ psum, __hip_bfloat16* __restrict__ Cout) {
    __shared__ short As[128 * ASTR];
    __shared__ short Bh[128 * ASTR];
    __shared__ short Bl[128 * ASTR];
    int r0 = blockIdx.x * 128;
    int n0 = blockIdx.y * 128;
    int tid = threadIdx.x;
    int lane = tid & 63;
    int wm = ((tid >> 6) >> 1) * 64, wn = ((tid >> 6) & 1) * 64;

    f32x4 acc[4][4];
#pragma unroll
    for (int i = 0; i < 4; i++)
#pragma unroll
        for (int j = 0; j < 4; j++) acc[i][j] = (f32x4){0.f, 0.f, 0.f, 0.f};

    for (int k0 = 0; k0 < K; k0 += 32) {
        __syncthreads();
        // stage A tile: 128 rows x 32 bf16 (8KB) as 512 x 16B, 2 per thread
#pragma unroll
        for (int j = 0; j < 2; j++) {
            int i = tid + j * 256;
            int row = i >> 2, cb = i & 3;
            int grow = r0 + row;
            if (grow >= M) grow = M - 1;
            int4 v = *(const int4*)(A + (size_t)grow * K + k0 + cb * 8);
            *(int4*)(As + row * ASTR + cb * 8) = v;
        }
        // stage B hi/lo tiles (n-major [N][K] -> rows are n)
#pragma unroll
        for (int j = 0; j < 2; j++) {
            int i = tid + j * 256;
            int row = i >> 2, cb = i & 3;
            size_t go = (size_t)(n0 + row) * K + k0 + cb * 8;
            *(int4*)(Bh + row * ASTR + cb * 8) = *(const int4*)(Bhi + go);
            *(int4*)(Bl + row * ASTR + cb * 8) = *(const int4*)(Blo + go);
        }
        __syncthreads();
        // fragments: lane&15 = free index, k = 8*(lane>>4) + 0..7 contiguous
        int fi = lane & 15, kb = (lane >> 4) * 8;
        bf16x8 af[4], bhf[4], blf[4];
#pragma unroll
        for (int mi = 0; mi < 4; mi++)
            af[mi] = *(const bf16x8*)(As + (wm + mi * 16 + fi) * ASTR + kb);
#pragma unroll
        for (int ni = 0; ni < 4; ni++) {
            bhf[ni] = *(const bf16x8*)(Bh + (wn + ni * 16 + fi) * ASTR + kb);
            blf[ni] = *(const bf16x8*)(Bl + (wn + ni * 16 + fi) * ASTR + kb);
        }
#pragma unroll
        for (int mi = 0; mi < 4; mi++)
#pragma unroll
            for (int ni = 0; ni < 4; ni++) {
                acc[mi][ni] = __builtin_amdgcn_mfma_f32_16x16x32_bf16(af[mi], bhf[ni],
                                                                     acc[mi][ni], 0, 0, 0);
                acc[mi][ni] = __builtin_amdgcn_mfma_f32_16x16x32_bf16(af[mi], blf[ni],
                                                                     acc[mi][ni], 0, 0, 0);
            }
    }
    // epilogue: C/D layout col = lane&15, row = 4*(lane>>4) + reg
    int col_l = lane & 15, quad = lane >> 4;
#pragma unroll
    for (int mi = 0; mi < 4; mi++) {
        int rbase = r0 + wm + mi * 16 + quad * 4;
#pragma unroll
        for (int ni = 0; ni < 4; ni++) {
            int gcol = n0 + wn + ni * 16 + col_l;
            if (MODE == 0) {
                float b0 = bias[gcol];
#pragma unroll
                for (int reg = 0; reg < 4; reg++) {
                    int grow = rbase + reg;
                    if (grow < M)
                        Cout[(size_t)grow * N + gcol] = __float2bfloat16(acc[mi][ni][reg] + b0);
                }
            } else {
                float b0 = bias[gcol], g0 = bng[gcol], bb0 = bnb[gcol];
                float vv[4];
#pragma unroll
                for (int reg = 0; reg < 4; reg++)
                    vv[reg] = fmaxf(fmaf((acc[mi][ni][reg] + b0) * bn_inv(), g0, bb0), 0.f);
                if (MODE == 1) {
#pragma unroll
                    for (int reg = 0; reg < 4; reg++) {
                        int grow = rbase + reg;
                        if (grow < M) Cout[(size_t)grow * 512 + gcol] = __float2bfloat16(vv[reg]);
                    }
                } else {
                    if (rbase + 3 < M && batch[rbase] == batch[rbase + 3]) {
                        atomicAdd(&psum[(size_t)batch[rbase] * 512 + gcol],
                                  (vv[0] + vv[1]) + (vv[2] + vv[3]));
                    } else {
#pragma unroll
                        for (int reg = 0; reg < 4; reg++) {
                            int grow = rbase + reg;
                            if (grow < M)
                                atomicAdd(&psum[(size_t)batch[grow] * 512 + gcol], vv[reg]);
                        }
                    }
                }
            }
        }
    }
}

// ---------------- GINE1: per-edge message + scatter (64 dims, 1 wave/edge) ---
__global__ void gine1_msg(const float* __restrict__ x, const int* __restrict__ src,
                          const int* __restrict__ dst, const float* __restrict__ ea,
                          const float* __restrict__ e1W, const float* __restrict__ e1b,
                          float* __restrict__ aggr) {
    int e = blockIdx.x * 4 + (threadIdx.x >> 6);
    int lane = threadIdx.x & 63;
    if (e >= N_EDGESC) return;
    int s = src[e], d = dst[e];
    float acc = e1b[lane];
    const float* eap = ea + (size_t)e * EDIM;
#pragma unroll
    for (int k = 0; k < EDIM; k++) acc = fmaf(eap[k], e1W[k * NDIM + lane], acc);
    float m = x[(size_t)s * NDIM + lane] + acc;
    atomicAdd(&aggr[(size_t)d * NDIM + lane], fmaxf(m, 0.f));
}

// ---------------- XIN = bf16(x + aggr1) --------------------------------------
__global__ void xin_build(const float* __restrict__ x, const float* __restrict__ aggr,
                          __hip_bfloat16* __restrict__ xin) {
    int i = blockIdx.x * 256 + threadIdx.x;
    if (i < N_NODESC * NDIM) xin[i] = __float2bfloat16(x[i] + aggr[i]);
}

// ---------------- A2 = bf16(h + aggr2_chunk) ---------------------------------
__global__ void a2_build(const __hip_bfloat16* __restrict__ h, const float* __restrict__ aggr,
                         __hip_bfloat16* __restrict__ a2, int n) {
    int i = (blockIdx.x * 256 + threadIdx.x) * 4;
    if (i >= n) return;
    short4 hv = *(const short4*)((const short*)h + i);
    float4 av = *(const float4*)(aggr + i);
    __hip_bfloat16 o[4];
    const __hip_bfloat16* hb = (const __hip_bfloat16*)&hv;
    o[0] = __float2bfloat16(__bfloat162float(hb[0]) + av.x);
    o[1] = __float2bfloat16(__bfloat162float(hb[1]) + av.y);
    o[2] = __float2bfloat16(__bfloat162float(hb[2]) + av.z);
    o[3] = __float2bfloat16(__bfloat162float(hb[3]) + av.w);
    *(short4*)((short*)a2 + i) = *(const short4*)o;
}

// ---------------- GINE2 msg, chunked over dst (1 wave/edge) ------------------
__global__ void gine2_msg_chunk(const __hip_bfloat16* __restrict__ h,
                                const int* __restrict__ src, const int* __restrict__ dst,
                                const float* __restrict__ ea, const float* __restrict__ e2W,
                                const float* __restrict__ e2b, float* __restrict__ aggrc,
                                int c0n, int c1n) {
    int e = blockIdx.x * 4 + (threadIdx.x >> 6);
    int lane = threadIdx.x & 63;
    if (e >= N_EDGESC) return;
    int d = dst[e];
    if (d < c0n || d >= c1n) return;
    int s = src[e];
    const float* eap = ea + (size_t)e * EDIM;
    float ev[16];
#pragma unroll
    for (int k = 0; k < 16; k++) ev[k] = eap[k];
    const __hip_bfloat16* hp = h + (size_t)s * 512;
    float* ap = aggrc + (size_t)(d - c0n) * 512;
#pragma unroll
    for (int j = 0; j < 8; j++) {
        int c = lane + j * 64;
        float acc = e2b[c];
#pragma unroll
        for (int k = 0; k < 16; k++) acc = fmaf(ev[k], e2W[k * 512 + c], acc);
        float m = __bfloat162float(hp[c]) + acc;
        atomicAdd(ap + c, fmaxf(m, 0.f));
    }
}

// ---------------- node counts per graph --------------------------------------
__global__ void count_nodes(const int* __restrict__ batch, float* __restrict__ cnt) {
    int i = blockIdx.x * 256 + threadIdx.x;
    if (i < N_NODESC) atomicAdd(&cnt[batch[i]], 1.0f);
}

// ---------------- finalize pool + assemble xn [B,7,512] bf16 -----------------
__global__ void build_xn(const float* __restrict__ psum, const float* __restrict__ cnt,
                         const float* __restrict__ ecfp, const float* __restrict__ topo,
                         const float* __restrict__ maccs, const float* __restrict__ estate,
                         const float* __restrict__ rdkit2d, const float* __restrict__ phar2d,
                         __hip_bfloat16* __restrict__ xn) {
    int i = blockIdx.x * 256 + threadIdx.x;
    if (i >= BG * 512) return;
    int bidx = i >> 9, c = i & 511;
    float cv = fmaxf(cnt[bidx], 1.0f);
    __hip_bfloat16* o = xn + (size_t)bidx * 7 * 512;
    o[c] = __float2bfloat16(psum[i] / cv);
    o[512 + c] = __float2bfloat16(ecfp[i]);
    o[2 * 512 + c] = __float2bfloat16(topo[i]);
    o[3 * 512 + c] = __float2bfloat16(maccs[i]);
    o[4 * 512 + c] = __float2bfloat16(estate[i]);
    o[5 * 512 + c] = __float2bfloat16(rdkit2d[i]);
    o[6 * 512 + c] = __float2bfloat16(phar2d[i]);
}

// ---------------- GAT attention + aggregate + bn + relu (1 block/graph) ------
__global__ void gat_attn(const __hip_bfloat16* __restrict__ gl,
                         const __hip_bfloat16* __restrict__ gr,
                         const float* __restrict__ att, const float* __restrict__ bias,
                         const float* __restrict__ bng, const float* __restrict__ bnb,
                         __hip_bfloat16* __restrict__ zout) {
    int b = blockIdx.x;
    int tid = threadIdx.x;
    int wave = tid >> 6, lane = tid & 63;
    __shared__ float logits[13][4];
    __shared__ float alpha[13][4];
    const size_t base = (size_t)b * 7 * 4 * 512;
    for (int p = wave; p < 52; p += 4) {
        int e = p >> 2, hh = p & 3;
        int se = (e < 7) ? 0 : (e - 6);
        int de = (e < 6) ? (e + 1) : ((e == 6) ? 0 : (e - 6));
        const __hip_bfloat16* glp = gl + base + (size_t)(se * 4 + hh) * 512;
        const __hip_bfloat16* grp = gr + base + (size_t)(de * 4 + hh) * 512;
        const float* ap = att + hh * 512;
        float s = 0.f;
#pragma unroll
        for (int j = 0; j < 8; j++) {
            int c = lane + j * 64;
            float v = __bfloat162float(glp[c]) + __bfloat162float(grp[c]);
            v = (v >= 0.f) ? v : 0.2f * v;
            s = fmaf(v, ap[c], s);
        }
#pragma unroll
        for (int off = 32; off; off >>= 1) s += __shfl_down(s, off);
        if (lane == 0) logits[e][hh] = s;
    }
    __syncthreads();
    if (tid < 24) {
        int n = 1 + (tid >> 2), hh = tid & 3;
        float la = logits[n - 1][hh], lb = logits[6 + n][hh];
        float m = fmaxf(la, lb);
        float ea = __expf(la - m), eb = __expf(lb - m);
        float inv = 1.f / (ea + eb);
        alpha[n - 1][hh] = ea * inv;
        alpha[6 + n][hh] = eb * inv;
    } else if (tid < 28) {
        alpha[6][tid & 3] = 1.f;
    }
    __syncthreads();
    for (int i = tid; i < 7 * 512; i += 256) {
        int n = i >> 9, c = i & 511;
        float v = 0.f;
        if (n == 0) {
#pragma unroll
            for (int hh = 0; hh < 4; hh++)
                v = fmaf(alpha[6][hh], __bfloat162float(gl[base + (size_t)hh * 512 + c]), v);
        } else {
#pragma unroll
            for (int hh = 0; hh < 4; hh++) {
                v = fmaf(alpha[n - 1][hh], __bfloat162float(gl[base + (size_t)hh * 512 + c]), v);
                v = fmaf(alpha[6 + n][hh],
                         __bfloat162float(gl[base + (size_t)(n * 4 + hh) * 512 + c]), v);
            }
        }
        v = fmaf(v, 0.25f, bias[c]);
        v = fmaf(v * bn_inv(), bng[c], bnb[c]);
        zout[(size_t)b * 7 * 512 + i] = __float2bfloat16(fmaxf(v, 0.f));
    }
}

// ---------------- final fc: out[b] = z2[b,0,:]@fc_W + fc_b -------------------
__global__ void final_fc(const __hip_bfloat16* __restrict__ z, const float* __restrict__ fcW,
                         const float* __restrict__ fcb, float* __restrict__ out) {
    int b = blockIdx.x * 4 + (threadIdx.x >> 6);
    int lane = threadIdx.x & 63;
    if (b >= BG) return;
    const __hip_bfloat16* row = z + (size_t)b * 7 * 512;
    float s = 0.f;
#pragma unroll
    for (int j = 0; j < 8; j++)
        s = fmaf(__bfloat162float(row[lane + j * 64]), fcW[lane + j * 64], s);
#pragma unroll
    for (int off = 32; off; off >>= 1) s += __shfl_down(s, off);
    if (lane == 0) out[b] = s + fcb[0];
}

extern "C" void kernel_launch(void* const* d_in, const int* in_sizes, int n_in,
                              void* d_out, int out_size, void* d_ws, size_t ws_size,
                              hipStream_t stream) {
    const float* x = (const float*)d_in[0];
    const int* eidx = (const int*)d_in[1];
    const float* eattr = (const float*)d_in[2];
    const int* batch = (const int*)d_in[3];
    const float* ecfp = (const float*)d_in[4];
    const float* topo = (const float*)d_in[5];
    const float* maccs = (const float*)d_in[6];
    const float* estate = (const float*)d_in[7];
    const float* rdkit2d = (const float*)d_in[8];
    const float* phar2d = (const float*)d_in[9];
    const float* g1_W = (const float*)d_in[10];
    const float* g1_b = (const float*)d_in[11];
    const float* e1_W = (const float*)d_in[12];
    const float* e1_b = (const float*)d_in[13];
    const float* bn1_g = (const float*)d_in[14];
    const float* bn1_b = (const float*)d_in[15];
    const float* g2_W = (const float*)d_in[16];
    const float* g2_b = (const float*)d_in[17];
    const float* e2_W = (const float*)d_in[18];
    const float* e2_b = (const float*)d_in[19];
    const float* bn2_g = (const float*)d_in[20];
    const float* bn2_b = (const float*)d_in[21];
    const float* gat1_Wl = (const float*)d_in[22];
    const float* gat1_bl = (const float*)d_in[23];
    const float* gat1_Wr = (const float*)d_in[24];
    const float* gat1_br = (const float*)d_in[25];
    const float* gat1_att = (const float*)d_in[26];
    const float* gat1_bias = (const float*)d_in[27];
    const float* bn3_g = (const float*)d_in[28];
    const float* bn3_b = (const float*)d_in[29];
    const float* gat2_Wl = (const float*)d_in[30];
    const float* gat2_bl = (const float*)d_in[31];
    const float* gat2_Wr = (const float*)d_in[32];
    const float* gat2_br = (const float*)d_in[33];
    const float* gat2_att = (const float*)d_in[34];
    const float* gat2_bias = (const float*)d_in[35];
    const float* bn4_g = (const float*)d_in[36];
    const float* bn4_b = (const float*)d_in[37];
    const float* fc_W = (const float*)d_in[38];
    const float* fc_b = (const float*)d_in[39];
    float* out = (float*)d_out;

    // ---- workspace layout (byte offsets; total = 194,682,880, proven fit) ----
    // R1 [0, 102.4M):      GINE: H bf16 100000x512
    //                      GAT : GL bf16 @0 (58,720,256), Z1B bf16 @58,720,256
    //                            (14,680,064), GATW hi/lo bf16 @73,400,320 (16,777,216)
    // R2 [102.4M, 161.1M): GINE1: AGG1 f32 @+0 (25.6M), XIN bf16 @+25,600,000 (12.8M)
    //                      GINE2: AGG2 f32 @+0 (26,214,400), A2 bf16 @+26,214,400 (13.1M)
    //                      GAT  : GR bf16 @+0 (58,720,256)
    // R3 [161.1M, 190.5M): GINE: g1Wt hi/lo (131,072), g2Wt hi/lo (1,048,576)
    //                      GAT : XNB bf16 @+0 (14,680,064), Z2B bf16 @+14,680,064
    // PS  @190,480,384 (4,194,304), PC @194,674,688 (8,192)
    const size_t NEEDED = 194682880ull;
    if (ws_size < NEEDED) {
        zero_out<<<(BG + 255) / 256, 256, 0, stream>>>(out, BG);
        return;
    }
    char* w = (char*)d_ws;
    __hip_bfloat16* H = (__hip_bfloat16*)w;
    __hip_bfloat16* GL = (__hip_bfloat16*)w;
    __hip_bfloat16* Z1B = (__hip_bfloat16*)(w + 58720256);
    __hip_bfloat16* GW1L_h = (__hip_bfloat16*)(w + 73400320);
    __hip_bfloat16* GW1L_l = GW1L_h + 2048 * 512;
    __hip_bfloat16* GW1R_h = GW1L_l + 2048 * 512;
    __hip_bfloat16* GW1R_l = GW1R_h + 2048 * 512;
    __hip_bfloat16* GW2L_h = GW1R_l + 2048 * 512;
    __hip_bfloat16* GW2L_l = GW2L_h + 2048 * 512;
    __hip_bfloat16* GW2R_h = GW2L_l + 2048 * 512;
    __hip_bfloat16* GW2R_l = GW2R_h + 2048 * 512;

    float* AGG1 = (float*)(w + 102400000);
    __hip_bfloat16* XIN = (__hip_bfloat16*)(w + 102400000 + 25600000);
    float* AGG2 = (float*)(w + 102400000);
    __hip_bfloat16* A2 = (__hip_bfloat16*)(w + 102400000 + 26214400);
    __hip_bfloat16* GR = (__hip_bfloat16*)(w + 102400000);

    __hip_bfloat16* G1W_h = (__hip_bfloat16*)(w + 161120256);
    __hip_bfloat16* G1W_l = G1W_h + 512 * 64;
    __hip_bfloat16* G2W_h = G1W_l + 512 * 64;
    __hip_bfloat16* G2W_l = G2W_h + 512 * 512;
    __hip_bfloat16* XNB = (__hip_bfloat16*)(w + 161120256);
    __hip_bfloat16* Z2B = (__hip_bfloat16*)(w + 161120256 + 14680064);

    float* PS = (float*)(w + 190480384);
    float* PC = (float*)(w + 194674688);

    const int* src = eidx;
    const int* dst = eidx + N_EDGESC;

    // ---- weight prep (GINE) ----
    transpose_wt<<<dim3(1, 8), 256, 0, stream>>>(g1_W, G1W_h, G1W_l, 64, 512);
    transpose_wt<<<dim3(8, 8), 256, 0, stream>>>(g2_W, G2W_h, G2W_l, 512, 512);

    // ---- GINE1 ----
    zero_f4<<<(N_NODESC * NDIM / 4 + 255) / 256, 256, 0, stream>>>((float4*)AGG1,
                                                                   N_NODESC * NDIM / 4);
    zero_f4<<<(BG * 512 / 4 + 255) / 256, 256, 0, stream>>>((float4*)PS, BG * 512 / 4);
    zero_f4<<<(BG / 4 + 255) / 256, 256, 0, stream>>>((float4*)PC, BG / 4);
    gine1_msg<<<N_EDGESC / 4, 256, 0, stream>>>(x, src, dst, eattr, e1_W, e1_b, AGG1);
    xin_build<<<(N_NODESC * NDIM + 255) / 256, 256, 0, stream>>>(x, AGG1, XIN);
    mfma_gemm<1><<<dim3((N_NODESC + 127) / 128, 4), 256, 0, stream>>>(
        XIN, G1W_h, G1W_l, N_NODESC, 64, 512, g1_b, bn1_g, bn1_b, nullptr, nullptr, H);
    count_nodes<<<(N_NODESC + 255) / 256, 256, 0, stream>>>(batch, PC);

    // ---- GINE2, chunked over dst nodes ----
    for (int c0n = 0; c0n < N_NODESC; c0n += CH) {
        int c1n = c0n + CH < N_NODESC ? c0n + CH : N_NODESC;
        int rows = c1n - c0n;
        int n = rows * 512;
        zero_f4<<<(n / 4 + 255) / 256, 256, 0, stream>>>((float4*)AGG2, n / 4);
        gine2_msg_chunk<<<N_EDGESC / 4, 256, 0, stream>>>(H, src, dst, eattr, e2_W, e2_b,
                                                          AGG2, c0n, c1n);
        a2_build<<<(n / 4 + 255) / 256, 256, 0, stream>>>(H + (size_t)c0n * 512, AGG2, A2, n);
        mfma_gemm<2><<<dim3((rows + 127) / 128, 4), 256, 0, stream>>>(
            A2, G2W_h, G2W_l, rows, 512, 512, g2_b, bn2_g, bn2_b, batch + c0n, PS, nullptr);
    }

    // ---- GAT weight prep (H now dead past 73.4MB) ----
    transpose_wt<<<dim3(8, 32), 256, 0, stream>>>(gat1_Wl, GW1L_h, GW1L_l, 512, 2048);
    transpose_wt<<<dim3(8, 32), 256, 0, stream>>>(gat1_Wr, GW1R_h, GW1R_l, 512, 2048);
    transpose_wt<<<dim3(8, 32), 256, 0, stream>>>(gat2_Wl, GW2L_h, GW2L_l, 512, 2048);
    transpose_wt<<<dim3(8, 32), 256, 0, stream>>>(gat2_Wr, GW2R_h, GW2R_l, 512, 2048);

    // ---- pool -> xn (bf16) ----
    build_xn<<<(BG * 512) / 256, 256, 0, stream>>>(PS, PC, ecfp, topo, maccs, estate,
                                                   rdkit2d, phar2d, XNB);
    // ---- GAT layer 1 ----
    const int MGAT = BG * 7;  // 14336
    dim3 ggrid(MGAT / 128, 16);
    mfma_gemm<0><<<ggrid, 256, 0, stream>>>(XNB, GW1L_h, GW1L_l, MGAT, 512, 2048, gat1_bl,
                                            nullptr, nullptr, nullptr, nullptr, GL);
    mfma_gemm<0><<<ggrid, 256, 0, stream>>>(XNB, GW1R_h, GW1R_l, MGAT, 512, 2048, gat1_br,
                                            nullptr, nullptr, nullptr, nullptr, GR);
    gat_attn<<<BG, 256, 0, stream>>>(GL, GR, gat1_att, gat1_bias, bn3_g, bn3_b, Z1B);
    // ---- GAT layer 2 ----
    mfma_gemm<0><<<ggrid, 256, 0, stream>>>(Z1B, GW2L_h, GW2L_l, MGAT, 512, 2048, gat2_bl,
                                            nullptr, nullptr, nullptr, nullptr, GL);
    mfma_gemm<0><<<ggrid, 256, 0, stream>>>(Z1B, GW2R_h, GW2R_l, MGAT, 512, 2048, gat2_br,
                                            nullptr, nullptr, nullptr, nullptr, GR);
    gat_attn<<<BG, 256, 0, stream>>>(GL, GR, gat2_att, gat2_bias, bn4_g, bn4_b, Z2B);
    // ---- final fc ----
    final_fc<<<BG / 4, 256, 0, stream>>>(Z2B, fc_W, fc_b, out);
}

// Round 4
// 1090.514 us; speedup vs baseline: 3.3748x; 1.4677x over previous
//
#include <hip/hip_runtime.h>
#include <hip/hip_bf16.h>

#define N_NODESC 100000
#define N_EDGESC 200000
#define BG 2048
#define NDIM 64
#define EDIM 16

typedef __bf16 bf16x8 __attribute__((ext_vector_type(8)));
typedef float f32x4 __attribute__((ext_vector_type(4)));

static __device__ __forceinline__ float bn_inv() { return 0.9999950000374997f; }

// ---------------- zero fills --------------------------------------------------
__global__ void zero_f4(float4* __restrict__ p, int n4) {
    int i = blockIdx.x * 256 + threadIdx.x;
    if (i < n4) p[i] = make_float4(0.f, 0.f, 0.f, 0.f);
}
__global__ void zero_int(int* __restrict__ p, int n) {
    int i = blockIdx.x * 256 + threadIdx.x;
    if (i < n) p[i] = 0;
}
__global__ void zero_out(float* __restrict__ p, int n) {
    int i = blockIdx.x * 256 + threadIdx.x;
    if (i < n) p[i] = 0.f;
}

// ---------------- CSR build: histogram -> scan -> scatter --------------------
__global__ void hist_dst(const int* __restrict__ dst, int* __restrict__ deg) {
    int i = blockIdx.x * 256 + threadIdx.x;
    if (i < N_EDGESC) atomicAdd(&deg[dst[i]], 1);
}
// block sums over 1024-elem blocks
__global__ void scan_bsums(const int* __restrict__ deg, int* __restrict__ bsum, int n) {
    __shared__ int ls[256];
    int b = blockIdx.x, t = threadIdx.x;
    int s = 0;
#pragma unroll
    for (int j = 0; j < 4; j++) {
        int i = b * 1024 + t * 4 + j;
        if (i < n) s += deg[i];
    }
    ls[t] = s;
    __syncthreads();
    for (int off = 128; off; off >>= 1) {
        if (t < off) ls[t] += ls[t + off];
        __syncthreads();
    }
    if (t == 0) bsum[b] = ls[0];
}
__global__ void scan_top(int* __restrict__ bsum, int nb, int* __restrict__ total) {
    if (threadIdx.x == 0) {
        int acc = 0;
        for (int i = 0; i < nb; i++) { int v = bsum[i]; bsum[i] = acc; acc += v; }
        *total = acc;
    }
}
__global__ void scan_final(const int* __restrict__ deg, const int* __restrict__ bsum,
                           int* __restrict__ rowptr, int* __restrict__ cursor, int n) {
    __shared__ int ls[256];
    int b = blockIdx.x, t = threadIdx.x;
    int v[4], s = 0;
#pragma unroll
    for (int j = 0; j < 4; j++) {
        int i = b * 1024 + t * 4 + j;
        v[j] = (i < n) ? deg[i] : 0;
        s += v[j];
    }
    ls[t] = s;
    __syncthreads();
    int run = s;
    for (int off = 1; off < 256; off <<= 1) {
        int add = (t >= off) ? ls[t - off] : 0;
        __syncthreads();
        ls[t] += add;
        __syncthreads();
    }
    int excl = ls[t] - run + bsum[b];
#pragma unroll
    for (int j = 0; j < 4; j++) {
        int i = b * 1024 + t * 4 + j;
        if (i < n) { rowptr[i] = excl; cursor[i] = excl; excl += v[j]; }
    }
}
__global__ void scatter_eid(const int* __restrict__ dst, int* __restrict__ cursor,
                            int* __restrict__ eid) {
    int e = blockIdx.x * 256 + threadIdx.x;
    if (e < N_EDGESC) {
        int p = atomicAdd(&cursor[dst[e]], 1);
        eid[p] = e;
    }
}

// ---------------- W [K][N] f32 -> bf16 [N][K] --------------------------------
__global__ void transpose_w(const float* __restrict__ W, __hip_bfloat16* __restrict__ hi,
                            int K, int N) {
    __shared__ float t[64][65];
    int k0 = blockIdx.x * 64, n0 = blockIdx.y * 64;
    int tid = threadIdx.x, tx = tid & 63, ty = tid >> 6;
    for (int r = ty; r < 64; r += 4) t[r][tx] = W[(size_t)(k0 + r) * N + n0 + tx];
    __syncthreads();
    for (int r = ty; r < 64; r += 4)
        hi[(size_t)(n0 + r) * K + k0 + tx] = __float2bfloat16(t[tx][r]);
}

// ---------------- GINE1 gather: xin = bf16(x[n] + sum relu(x[src]+ea@W+b)) ---
// 1 wave/node, lane = dim; e1W cached in 16 regs/lane.
__global__ __launch_bounds__(256) void gine1_gather(
    const float* __restrict__ x, const int* __restrict__ srcv, const float* __restrict__ ea,
    const float* __restrict__ e1W, const float* __restrict__ e1b,
    const int* __restrict__ rowptr, const int* __restrict__ eid,
    __hip_bfloat16* __restrict__ xin) {
    int tid = threadIdx.x;
    int wave = tid >> 6, lane = tid & 63;
    int n = blockIdx.x * 4 + wave;
    if (n >= N_NODESC) return;
    float wreg[16];
#pragma unroll
    for (int k = 0; k < 16; k++) wreg[k] = e1W[k * 64 + lane];
    float bb = e1b[lane];
    float acc = x[(size_t)n * 64 + lane];
    int beg = rowptr[n], end = rowptr[n + 1];
    for (int idx = beg; idx < end; idx++) {
        int e = eid[idx], s = srcv[e];
        const float* eap = ea + (size_t)e * 16;
        float p = bb;
#pragma unroll
        for (int k = 0; k < 16; k++) p = fmaf(eap[k], wreg[k], p);
        acc += fmaxf(x[(size_t)s * 64 + lane] + p, 0.f);
    }
    xin[(size_t)n * 64 + lane] = __float2bfloat16(acc);
}

// ---------------- GINE2 gather: a2 = bf16(h[n] + sum relu(h[src]+ea@W+b)) ----
// 2 nodes/block (128 thr each), 4 dims/thread; e2W slice in 64 regs/thread.
__global__ __launch_bounds__(256) void gine2_gather(
    const __hip_bfloat16* __restrict__ h, const int* __restrict__ srcv,
    const float* __restrict__ ea, const float* __restrict__ e2W,
    const float* __restrict__ e2b, const int* __restrict__ rowptr,
    const int* __restrict__ eid, __hip_bfloat16* __restrict__ a2, int n0, int n1) {
    int tid = threadIdx.x;
    int half = tid >> 7, lt = tid & 127;
    int n = n0 + blockIdx.x * 2 + half;
    if (n >= n1) return;
    float wreg[4][16], breg[4], acc[4];
#pragma unroll
    for (int j = 0; j < 4; j++) {
        int c = lt + j * 128;
        breg[j] = e2b[c];
#pragma unroll
        for (int k = 0; k < 16; k++) wreg[j][k] = e2W[k * 512 + c];
    }
    const __hip_bfloat16* hn = h + (size_t)n * 512;
#pragma unroll
    for (int j = 0; j < 4; j++) acc[j] = __bfloat162float(hn[lt + j * 128]);
    int beg = rowptr[n], end = rowptr[n + 1];
    for (int idx = beg; idx < end; idx++) {
        int e = eid[idx], s = srcv[e];
        const float* eap = ea + (size_t)e * 16;
        float ev[16];
#pragma unroll
        for (int k = 0; k < 16; k++) ev[k] = eap[k];
        const __hip_bfloat16* hs = h + (size_t)s * 512;
#pragma unroll
        for (int j = 0; j < 4; j++) {
            int c = lt + j * 128;
            float p = breg[j];
#pragma unroll
            for (int k = 0; k < 16; k++) p = fmaf(ev[k], wreg[j][k], p);
            acc[j] += fmaxf(__bfloat162float(hs[c]) + p, 0.f);
        }
    }
    __hip_bfloat16* an = a2 + (size_t)(n - n0) * 512;
#pragma unroll
    for (int j = 0; j < 4; j++) an[lt + j * 128] = __float2bfloat16(acc[j]);
}

// ---------------- MFMA GEMM: C[M,N] = A[M,K](bf16) @ B^T[N,K](bf16) ----------
// 128x128 tile, 256 threads (4 waves 2x2), 4x4 16x16x32 acc/wave.
// MODE 0: C = acc + bias[n] -> bf16 Cout [M,N]
// MODE 1: C = relu(bn(acc+bias)) -> bf16 Cout [M,512]
// MODE 2: C = relu(bn(acc+bias)), atomicAdd psum[batch[m]*512+n]
#define ASTR 40
template <int MODE>
__global__ __launch_bounds__(256, 2) void mfma_gemm(
    const __hip_bfloat16* __restrict__ A, const __hip_bfloat16* __restrict__ Bhi,
    int M, int K, int N, const float* __restrict__ bias, const float* __restrict__ bng,
    const float* __restrict__ bnb, const int* __restrict__ batch,
    float* __restrict__ psum, __hip_bfloat16* __restrict__ Cout) {
    __shared__ short As[128 * ASTR];
    __shared__ short Bh[128 * ASTR];
    int r0 = blockIdx.x * 128;
    int n0 = blockIdx.y * 128;
    int tid = threadIdx.x;
    int lane = tid & 63;
    int wm = ((tid >> 6) >> 1) * 64, wn = ((tid >> 6) & 1) * 64;

    f32x4 acc[4][4];
#pragma unroll
    for (int i = 0; i < 4; i++)
#pragma unroll
        for (int j = 0; j < 4; j++) acc[i][j] = (f32x4){0.f, 0.f, 0.f, 0.f};

    for (int k0 = 0; k0 < K; k0 += 32) {
        __syncthreads();
#pragma unroll
        for (int j = 0; j < 2; j++) {
            int i = tid + j * 256;
            int row = i >> 2, cb = i & 3;
            int grow = r0 + row;
            if (grow >= M) grow = M - 1;
            *(int4*)(As + row * ASTR + cb * 8) =
                *(const int4*)(A + (size_t)grow * K + k0 + cb * 8);
        }
#pragma unroll
        for (int j = 0; j < 2; j++) {
            int i = tid + j * 256;
            int row = i >> 2, cb = i & 3;
            *(int4*)(Bh + row * ASTR + cb * 8) =
                *(const int4*)(Bhi + (size_t)(n0 + row) * K + k0 + cb * 8);
        }
        __syncthreads();
        int fi = lane & 15, kb = (lane >> 4) * 8;
        bf16x8 af[4], bhf[4];
#pragma unroll
        for (int mi = 0; mi < 4; mi++)
            af[mi] = *(const bf16x8*)(As + (wm + mi * 16 + fi) * ASTR + kb);
#pragma unroll
        for (int ni = 0; ni < 4; ni++)
            bhf[ni] = *(const bf16x8*)(Bh + (wn + ni * 16 + fi) * ASTR + kb);
#pragma unroll
        for (int mi = 0; mi < 4; mi++)
#pragma unroll
            for (int ni = 0; ni < 4; ni++)
                acc[mi][ni] = __builtin_amdgcn_mfma_f32_16x16x32_bf16(af[mi], bhf[ni],
                                                                     acc[mi][ni], 0, 0, 0);
    }
    int col_l = lane & 15, quad = lane >> 4;
#pragma unroll
    for (int mi = 0; mi < 4; mi++) {
        int rbase = r0 + wm + mi * 16 + quad * 4;
#pragma unroll
        for (int ni = 0; ni < 4; ni++) {
            int gcol = n0 + wn + ni * 16 + col_l;
            if (MODE == 0) {
                float b0 = bias[gcol];
#pragma unroll
                for (int reg = 0; reg < 4; reg++) {
                    int grow = rbase + reg;
                    if (grow < M)
                        Cout[(size_t)grow * N + gcol] = __float2bfloat16(acc[mi][ni][reg] + b0);
                }
            } else {
                float b0 = bias[gcol], g0 = bng[gcol], bb0 = bnb[gcol];
                float vv[4];
#pragma unroll
                for (int reg = 0; reg < 4; reg++)
                    vv[reg] = fmaxf(fmaf((acc[mi][ni][reg] + b0) * bn_inv(), g0, bb0), 0.f);
                if (MODE == 1) {
#pragma unroll
                    for (int reg = 0; reg < 4; reg++) {
                        int grow = rbase + reg;
                        if (grow < M) Cout[(size_t)grow * 512 + gcol] = __float2bfloat16(vv[reg]);
                    }
                } else {
                    if (rbase + 3 < M && batch[rbase] == batch[rbase + 3]) {
                        atomicAdd(&psum[(size_t)batch[rbase] * 512 + gcol],
                                  (vv[0] + vv[1]) + (vv[2] + vv[3]));
                    } else {
#pragma unroll
                        for (int reg = 0; reg < 4; reg++) {
                            int grow = rbase + reg;
                            if (grow < M)
                                atomicAdd(&psum[(size_t)batch[grow] * 512 + gcol], vv[reg]);
                        }
                    }
                }
            }
        }
    }
}

// ---------------- node counts per graph --------------------------------------
__global__ void count_nodes(const int* __restrict__ batch, float* __restrict__ cnt) {
    int i = blockIdx.x * 256 + threadIdx.x;
    if (i < N_NODESC) atomicAdd(&cnt[batch[i]], 1.0f);
}

// ---------------- finalize pool + assemble xn [B,7,512] bf16 -----------------
__global__ void build_xn(const float* __restrict__ psum, const float* __restrict__ cnt,
                         const float* __restrict__ ecfp, const float* __restrict__ topo,
                         const float* __restrict__ maccs, const float* __restrict__ estate,
                         const float* __restrict__ rdkit2d, const float* __restrict__ phar2d,
                         __hip_bfloat16* __restrict__ xn) {
    int i = blockIdx.x * 256 + threadIdx.x;
    if (i >= BG * 512) return;
    int bidx = i >> 9, c = i & 511;
    float cv = fmaxf(cnt[bidx], 1.0f);
    __hip_bfloat16* o = xn + (size_t)bidx * 7 * 512;
    o[c] = __float2bfloat16(psum[i] / cv);
    o[512 + c] = __float2bfloat16(ecfp[i]);
    o[2 * 512 + c] = __float2bfloat16(topo[i]);
    o[3 * 512 + c] = __float2bfloat16(maccs[i]);
    o[4 * 512 + c] = __float2bfloat16(estate[i]);
    o[5 * 512 + c] = __float2bfloat16(rdkit2d[i]);
    o[6 * 512 + c] = __float2bfloat16(phar2d[i]);
}

// ---------------- GAT attention + aggregate + bn + relu (1 block/graph) ------
__global__ void gat_attn(const __hip_bfloat16* __restrict__ gl,
                         const __hip_bfloat16* __restrict__ gr,
                         const float* __restrict__ att, const float* __restrict__ bias,
                         const float* __restrict__ bng, const float* __restrict__ bnb,
                         __hip_bfloat16* __restrict__ zout) {
    int b = blockIdx.x;
    int tid = threadIdx.x;
    int wave = tid >> 6, lane = tid & 63;
    __shared__ float logits[13][4];
    __shared__ float alpha[13][4];
    const size_t base = (size_t)b * 7 * 4 * 512;
    for (int p = wave; p < 52; p += 4) {
        int e = p >> 2, hh = p & 3;
        int se = (e < 7) ? 0 : (e - 6);
        int de = (e < 6) ? (e + 1) : ((e == 6) ? 0 : (e - 6));
        const __hip_bfloat16* glp = gl + base + (size_t)(se * 4 + hh) * 512;
        const __hip_bfloat16* grp = gr + base + (size_t)(de * 4 + hh) * 512;
        const float* ap = att + hh * 512;
        float s = 0.f;
#pragma unroll
        for (int j = 0; j < 8; j++) {
            int c = lane + j * 64;
            float v = __bfloat162float(glp[c]) + __bfloat162float(grp[c]);
            v = (v >= 0.f) ? v : 0.2f * v;
            s = fmaf(v, ap[c], s);
        }
#pragma unroll
        for (int off = 32; off; off >>= 1) s += __shfl_down(s, off);
        if (lane == 0) logits[e][hh] = s;
    }
    __syncthreads();
    if (tid < 24) {
        int n = 1 + (tid >> 2), hh = tid & 3;
        float la = logits[n - 1][hh], lb = logits[6 + n][hh];
        float m = fmaxf(la, lb);
        float ea = __expf(la - m), eb = __expf(lb - m);
        float inv = 1.f / (ea + eb);
        alpha[n - 1][hh] = ea * inv;
        alpha[6 + n][hh] = eb * inv;
    } else if (tid < 28) {
        alpha[6][tid & 3] = 1.f;
    }
    __syncthreads();
    for (int i = tid; i < 7 * 512; i += 256) {
        int n = i >> 9, c = i & 511;
        float v = 0.f;
        if (n == 0) {
#pragma unroll
            for (int hh = 0; hh < 4; hh++)
                v = fmaf(alpha[6][hh], __bfloat162float(gl[base + (size_t)hh * 512 + c]), v);
        } else {
#pragma unroll
            for (int hh = 0; hh < 4; hh++) {
                v = fmaf(alpha[n - 1][hh], __bfloat162float(gl[base + (size_t)hh * 512 + c]), v);
                v = fmaf(alpha[6 + n][hh],
                         __bfloat162float(gl[base + (size_t)(n * 4 + hh) * 512 + c]), v);
            }
        }
        v = fmaf(v, 0.25f, bias[c]);
        v = fmaf(v * bn_inv(), bng[c], bnb[c]);
        zout[(size_t)b * 7 * 512 + i] = __float2bfloat16(fmaxf(v, 0.f));
    }
}

// ---------------- final fc ----------------------------------------------------
__global__ void final_fc(const __hip_bfloat16* __restrict__ z, const float* __restrict__ fcW,
                         const float* __restrict__ fcb, float* __restrict__ out) {
    int b = blockIdx.x * 4 + (threadIdx.x >> 6);
    int lane = threadIdx.x & 63;
    if (b >= BG) return;
    const __hip_bfloat16* row = z + (size_t)b * 7 * 512;
    float s = 0.f;
#pragma unroll
    for (int j = 0; j < 8; j++)
        s = fmaf(__bfloat162float(row[lane + j * 64]), fcW[lane + j * 64], s);
#pragma unroll
    for (int off = 32; off; off >>= 1) s += __shfl_down(s, off);
    if (lane == 0) out[b] = s + fcb[0];
}

extern "C" void kernel_launch(void* const* d_in, const int* in_sizes, int n_in,
                              void* d_out, int out_size, void* d_ws, size_t ws_size,
                              hipStream_t stream) {
    const float* x = (const float*)d_in[0];
    const int* eidx = (const int*)d_in[1];
    const float* eattr = (const float*)d_in[2];
    const int* batch = (const int*)d_in[3];
    const float* ecfp = (const float*)d_in[4];
    const float* topo = (const float*)d_in[5];
    const float* maccs = (const float*)d_in[6];
    const float* estate = (const float*)d_in[7];
    const float* rdkit2d = (const float*)d_in[8];
    const float* phar2d = (const float*)d_in[9];
    const float* g1_W = (const float*)d_in[10];
    const float* g1_b = (const float*)d_in[11];
    const float* e1_W = (const float*)d_in[12];
    const float* e1_b = (const float*)d_in[13];
    const float* bn1_g = (const float*)d_in[14];
    const float* bn1_b = (const float*)d_in[15];
    const float* g2_W = (const float*)d_in[16];
    const float* g2_b = (const float*)d_in[17];
    const float* e2_W = (const float*)d_in[18];
    const float* e2_b = (const float*)d_in[19];
    const float* bn2_g = (const float*)d_in[20];
    const float* bn2_b = (const float*)d_in[21];
    const float* gat1_Wl = (const float*)d_in[22];
    const float* gat1_bl = (const float*)d_in[23];
    const float* gat1_Wr = (const float*)d_in[24];
    const float* gat1_br = (const float*)d_in[25];
    const float* gat1_att = (const float*)d_in[26];
    const float* gat1_bias = (const float*)d_in[27];
    const float* bn3_g = (const float*)d_in[28];
    const float* bn3_b = (const float*)d_in[29];
    const float* gat2_Wl = (const float*)d_in[30];
    const float* gat2_bl = (const float*)d_in[31];
    const float* gat2_Wr = (const float*)d_in[32];
    const float* gat2_br = (const float*)d_in[33];
    const float* gat2_att = (const float*)d_in[34];
    const float* gat2_bias = (const float*)d_in[35];
    const float* bn4_g = (const float*)d_in[36];
    const float* bn4_b = (const float*)d_in[37];
    const float* fc_W = (const float*)d_in[38];
    const float* fc_b = (const float*)d_in[39];
    float* out = (float*)d_out;

    // ---- workspace layout (byte offsets; total 194,682,880 — proven fit) ----
    // A [0, 102,400,000): H bf16 | GAT: GL @0 (58.72M), Z1B @58,720,256 (14.68M),
    //                     GW1L/GW1R/GW2L/GW2R bf16 @73,400,320 (4 x 2,097,152)
    // B [102,400,000, +58,720,256): A2 chunk bf16 (51.2M) | GAT: GR bf16
    // C [161,120,256, +29,360,128):
    //    +0:          XIN bf16 12.8M (GINE1) | XNB bf16 14.68M (GAT)
    //    +14,680,064: Z2B slot (attn2 output); during GINE holds:
    //                 ROWPTR +14,680,064 (400,128), CURSOR +15,080,192 (400,128),
    //                 EID +15,480,320 (800,000), DEG +16,280,320 (400,000),
    //                 G1W +16,680,320 (65,536), G2W +16,745,856 (524,288),
    //                 BSUM +17,270,144 (512)
    // PS @190,480,384 (4,194,304), PC @194,674,688 (8,192)
    const size_t NEEDED = 194682880ull;
    if (ws_size < NEEDED) {
        zero_out<<<(BG + 255) / 256, 256, 0, stream>>>(out, BG);
        return;
    }
    char* w = (char*)d_ws;
    __hip_bfloat16* H = (__hip_bfloat16*)w;
    __hip_bfloat16* GL = (__hip_bfloat16*)w;
    __hip_bfloat16* Z1B = (__hip_bfloat16*)(w + 58720256);
    __hip_bfloat16* GW1L = (__hip_bfloat16*)(w + 73400320);
    __hip_bfloat16* GW1R = GW1L + 2048 * 512;
    __hip_bfloat16* GW2L = GW1R + 2048 * 512;
    __hip_bfloat16* GW2R = GW2L + 2048 * 512;

    __hip_bfloat16* A2 = (__hip_bfloat16*)(w + 102400000);
    __hip_bfloat16* GR = (__hip_bfloat16*)(w + 102400000);

    char* C = w + 161120256;
    __hip_bfloat16* XIN = (__hip_bfloat16*)C;
    __hip_bfloat16* XNB = (__hip_bfloat16*)C;
    __hip_bfloat16* Z2B = (__hip_bfloat16*)(C + 14680064);
    int* ROWPTR = (int*)(C + 14680064);
    int* CURSOR = (int*)(C + 15080192);
    int* EID = (int*)(C + 15480320);
    int* DEG = (int*)(C + 16280320);
    __hip_bfloat16* G1W = (__hip_bfloat16*)(C + 16680320);
    __hip_bfloat16* G2W = (__hip_bfloat16*)(C + 16745856);
    int* BSUM = (int*)(C + 17270144);

    float* PS = (float*)(w + 190480384);
    float* PC = (float*)(w + 194674688);

    const int* src = eidx;
    const int* dst = eidx + N_EDGESC;

    // ---- CSR build ----
    zero_int<<<(N_NODESC + 255) / 256, 256, 0, stream>>>(DEG, N_NODESC);
    zero_f4<<<(BG * 512 / 4 + 255) / 256, 256, 0, stream>>>((float4*)PS, BG * 512 / 4);
    zero_f4<<<(BG / 4 + 255) / 256, 256, 0, stream>>>((float4*)PC, BG / 4);
    hist_dst<<<(N_EDGESC + 255) / 256, 256, 0, stream>>>(dst, DEG);
    const int NB = (N_NODESC + 1023) / 1024;  // 98
    scan_bsums<<<NB, 256, 0, stream>>>(DEG, BSUM, N_NODESC);
    scan_top<<<1, 64, 0, stream>>>(BSUM, NB, ROWPTR + N_NODESC);
    scan_final<<<NB, 256, 0, stream>>>(DEG, BSUM, ROWPTR, CURSOR, N_NODESC);
    scatter_eid<<<(N_EDGESC + 255) / 256, 256, 0, stream>>>(dst, CURSOR, EID);

    // ---- GINE weight prep ----
    transpose_w<<<dim3(1, 8), 256, 0, stream>>>(g1_W, G1W, 64, 512);
    transpose_w<<<dim3(8, 8), 256, 0, stream>>>(g2_W, G2W, 512, 512);

    // ---- GINE1 ----
    gine1_gather<<<(N_NODESC + 3) / 4, 256, 0, stream>>>(x, src, eattr, e1_W, e1_b,
                                                         ROWPTR, EID, XIN);
    mfma_gemm<1><<<dim3((N_NODESC + 127) / 128, 4), 256, 0, stream>>>(
        XIN, G1W, N_NODESC, 64, 512, g1_b, bn1_g, bn1_b, nullptr, nullptr, H);
    count_nodes<<<(N_NODESC + 255) / 256, 256, 0, stream>>>(batch, PC);

    // ---- GINE2: 2 chunks of 50k nodes ----
    for (int c0n = 0; c0n < N_NODESC; c0n += 50000) {
        int c1n = c0n + 50000;
        int rows = 50000;
        gine2_gather<<<rows / 2, 256, 0, stream>>>(H, src, eattr, e2_W, e2_b, ROWPTR, EID,
                                                   A2, c0n, c1n);
        mfma_gemm<2><<<dim3((rows + 127) / 128, 4), 256, 0, stream>>>(
            A2, G2W, rows, 512, 512, g2_b, bn2_g, bn2_b, batch + c0n, PS, nullptr);
    }

    // ---- GAT weight prep (H dead) ----
    transpose_w<<<dim3(8, 32), 256, 0, stream>>>(gat1_Wl, GW1L, 512, 2048);
    transpose_w<<<dim3(8, 32), 256, 0, stream>>>(gat1_Wr, GW1R, 512, 2048);
    transpose_w<<<dim3(8, 32), 256, 0, stream>>>(gat2_Wl, GW2L, 512, 2048);
    transpose_w<<<dim3(8, 32), 256, 0, stream>>>(gat2_Wr, GW2R, 512, 2048);

    // ---- pool -> xn ----
    build_xn<<<(BG * 512) / 256, 256, 0, stream>>>(PS, PC, ecfp, topo, maccs, estate,
                                                   rdkit2d, phar2d, XNB);
    // ---- GAT layer 1 ----
    const int MGAT = BG * 7;  // 14336
    dim3 ggrid(MGAT / 128, 16);
    mfma_gemm<0><<<ggrid, 256, 0, stream>>>(XNB, GW1L, MGAT, 512, 2048, gat1_bl,
                                            nullptr, nullptr, nullptr, nullptr, GL);
    mfma_gemm<0><<<ggrid, 256, 0, stream>>>(XNB, GW1R, MGAT, 512, 2048, gat1_br,
                                            nullptr, nullptr, nullptr, nullptr, GR);
    gat_attn<<<BG, 256, 0, stream>>>(GL, GR, gat1_att, gat1_bias, bn3_g, bn3_b, Z1B);
    // ---- GAT layer 2 ----
    mfma_gemm<0><<<ggrid, 256, 0, stream>>>(Z1B, GW2L, MGAT, 512, 2048, gat2_bl,
                                            nullptr, nullptr, nullptr, nullptr, GL);
    mfma_gemm<0><<<ggrid, 256, 0, stream>>>(Z1B, GW2R, MGAT, 512, 2048, gat2_br,
                                            nullptr, nullptr, nullptr, nullptr, GR);
    gat_attn<<<BG, 256, 0, stream>>>(GL, GR, gat2_att, gat2_bias, bn4_g, bn4_b, Z2B);
    // ---- final fc ----
    final_fc<<<BG / 4, 256, 0, stream>>>(Z2B, fc_W, fc_b, out);
}

// Round 5
// 1070.189 us; speedup vs baseline: 3.4388x; 1.0190x over previous
//
#include <hip/hip_runtime.h>
#include <hip/hip_bf16.h>

#define N_NODESC 100000
#define N_EDGESC 200000
#define BG 2048
#define NDIM 64
#define EDIM 16

typedef __bf16 bf16x8 __attribute__((ext_vector_type(8)));
typedef float f32x4 __attribute__((ext_vector_type(4)));

static __device__ __forceinline__ float bn_inv() { return 0.9999950000374997f; }

// ---------------- zero fills --------------------------------------------------
__global__ void zero_f4(float4* __restrict__ p, int n4) {
    int i = blockIdx.x * 256 + threadIdx.x;
    if (i < n4) p[i] = make_float4(0.f, 0.f, 0.f, 0.f);
}
__global__ void zero_int(int* __restrict__ p, int n) {
    int i = blockIdx.x * 256 + threadIdx.x;
    if (i < n) p[i] = 0;
}
__global__ void zero_out(float* __restrict__ p, int n) {
    int i = blockIdx.x * 256 + threadIdx.x;
    if (i < n) p[i] = 0.f;
}

// ---------------- CSR build: histogram -> scan -> scatter --------------------
__global__ void hist_dst(const int* __restrict__ dst, int* __restrict__ deg) {
    int i = blockIdx.x * 256 + threadIdx.x;
    if (i < N_EDGESC) atomicAdd(&deg[dst[i]], 1);
}
__global__ void scan_bsums(const int* __restrict__ deg, int* __restrict__ bsum, int n) {
    __shared__ int ls[256];
    int b = blockIdx.x, t = threadIdx.x;
    int s = 0;
#pragma unroll
    for (int j = 0; j < 4; j++) {
        int i = b * 1024 + t * 4 + j;
        if (i < n) s += deg[i];
    }
    ls[t] = s;
    __syncthreads();
    for (int off = 128; off; off >>= 1) {
        if (t < off) ls[t] += ls[t + off];
        __syncthreads();
    }
    if (t == 0) bsum[b] = ls[0];
}
__global__ void scan_top(int* __restrict__ bsum, int nb, int* __restrict__ total) {
    if (threadIdx.x == 0) {
        int acc = 0;
        for (int i = 0; i < nb; i++) { int v = bsum[i]; bsum[i] = acc; acc += v; }
        *total = acc;
    }
}
__global__ void scan_final(const int* __restrict__ deg, const int* __restrict__ bsum,
                           int* __restrict__ rowptr, int* __restrict__ cursor, int n) {
    __shared__ int ls[256];
    int b = blockIdx.x, t = threadIdx.x;
    int v[4], s = 0;
#pragma unroll
    for (int j = 0; j < 4; j++) {
        int i = b * 1024 + t * 4 + j;
        v[j] = (i < n) ? deg[i] : 0;
        s += v[j];
    }
    ls[t] = s;
    __syncthreads();
    int run = s;
    for (int off = 1; off < 256; off <<= 1) {
        int add = (t >= off) ? ls[t - off] : 0;
        __syncthreads();
        ls[t] += add;
        __syncthreads();
    }
    int excl = ls[t] - run + bsum[b];
#pragma unroll
    for (int j = 0; j < 4; j++) {
        int i = b * 1024 + t * 4 + j;
        if (i < n) { rowptr[i] = excl; cursor[i] = excl; excl += v[j]; }
    }
}
__global__ void scatter_eid(const int* __restrict__ dst, int* __restrict__ cursor,
                            int* __restrict__ eid) {
    int e = blockIdx.x * 256 + threadIdx.x;
    if (e < N_EDGESC) {
        int p = atomicAdd(&cursor[dst[e]], 1);
        eid[p] = e;
    }
}

// ---------------- W [K][N] f32 -> bf16 [N][K] --------------------------------
__global__ void transpose_w(const float* __restrict__ W, __hip_bfloat16* __restrict__ hi,
                            int K, int N) {
    __shared__ float t[64][65];
    int k0 = blockIdx.x * 64, n0 = blockIdx.y * 64;
    int tid = threadIdx.x, tx = tid & 63, ty = tid >> 6;
    for (int r = ty; r < 64; r += 4) t[r][tx] = W[(size_t)(k0 + r) * N + n0 + tx];
    __syncthreads();
    for (int r = ty; r < 64; r += 4)
        hi[(size_t)(n0 + r) * K + k0 + tx] = __float2bfloat16(t[tx][r]);
}

// ---------------- GINE1 gather: xin = bf16(x[n] + sum relu(x[src]+ea@W+b)) ---
// 1 wave handles 8 nodes sequentially; lane = dim; e1W cached in 16 regs/lane.
#define G1_NPW 8
__global__ __launch_bounds__(256, 2) void gine1_gather(
    const float* __restrict__ x, const int* __restrict__ srcv, const float* __restrict__ ea,
    const float* __restrict__ e1W, const float* __restrict__ e1b,
    const int* __restrict__ rowptr, const int* __restrict__ eid,
    __hip_bfloat16* __restrict__ xin) {
    int tid = threadIdx.x;
    int wave = tid >> 6, lane = tid & 63;
    float wreg[16];
#pragma unroll
    for (int k = 0; k < 16; k++) wreg[k] = e1W[k * 64 + lane];
    float bb = e1b[lane];
    int nbase = (blockIdx.x * 4 + wave) * G1_NPW;
#pragma unroll 1
    for (int it = 0; it < G1_NPW; it++) {
        int n = nbase + it;
        if (n >= N_NODESC) return;
        float acc = x[(size_t)n * 64 + lane];
        int beg = rowptr[n], end = rowptr[n + 1];
        for (int idx = beg; idx < end; idx++) {
            int e = eid[idx], s = srcv[e];
            const float4* ef = (const float4*)(ea + (size_t)e * 16);
            float4 e0 = ef[0], e1 = ef[1], e2 = ef[2], e3 = ef[3];
            float p = bb;
            p = fmaf(e0.x, wreg[0], p);  p = fmaf(e0.y, wreg[1], p);
            p = fmaf(e0.z, wreg[2], p);  p = fmaf(e0.w, wreg[3], p);
            p = fmaf(e1.x, wreg[4], p);  p = fmaf(e1.y, wreg[5], p);
            p = fmaf(e1.z, wreg[6], p);  p = fmaf(e1.w, wreg[7], p);
            p = fmaf(e2.x, wreg[8], p);  p = fmaf(e2.y, wreg[9], p);
            p = fmaf(e2.z, wreg[10], p); p = fmaf(e2.w, wreg[11], p);
            p = fmaf(e3.x, wreg[12], p); p = fmaf(e3.y, wreg[13], p);
            p = fmaf(e3.z, wreg[14], p); p = fmaf(e3.w, wreg[15], p);
            acc += fmaxf(x[(size_t)s * 64 + lane] + p, 0.f);
        }
        xin[(size_t)n * 64 + lane] = __float2bfloat16(acc);
    }
}

// ---------------- GINE2 gather: a2 = bf16(h[n] + sum relu(h[src]+ea@W+b)) ----
// 16 nodes/block (2 concurrent halves x 8 iters); thread owns cols lt*4..lt*4+3;
// e2W slice held in 64 VGPRs (launch_bounds(256,2) -> 256-VGPR budget).
#define G2_NPB 16
__global__ __launch_bounds__(256, 2) void gine2_gather(
    const __hip_bfloat16* __restrict__ h, const int* __restrict__ srcv,
    const float* __restrict__ ea, const float* __restrict__ e2W,
    const float* __restrict__ e2b, const int* __restrict__ rowptr,
    const int* __restrict__ eid, __hip_bfloat16* __restrict__ a2, int n0, int n1) {
    int tid = threadIdx.x;
    int half = tid >> 7, lt = tid & 127;
    float wreg[4][16], breg[4];
#pragma unroll
    for (int j = 0; j < 4; j++) {
        int c = lt * 4 + j;
        breg[j] = e2b[c];
#pragma unroll
        for (int k = 0; k < 16; k++) wreg[j][k] = e2W[k * 512 + c];
    }
    int nbase = n0 + blockIdx.x * G2_NPB + half;
#pragma unroll 1
    for (int it = 0; it < G2_NPB / 2; it++) {
        int n = nbase + it * 2;
        if (n >= n1) return;
        short4 hv = *(const short4*)((const short*)(h + (size_t)n * 512) + lt * 4);
        const __hip_bfloat16* hb = (const __hip_bfloat16*)&hv;
        float acc[4];
#pragma unroll
        for (int j = 0; j < 4; j++) acc[j] = __bfloat162float(hb[j]);
        int beg = rowptr[n], end = rowptr[n + 1];
        for (int idx = beg; idx < end; idx++) {
            int e = eid[idx], s = srcv[e];
            const float4* ef = (const float4*)(ea + (size_t)e * 16);
            float4 e0 = ef[0], e1 = ef[1], e2v = ef[2], e3 = ef[3];
            short4 sv = *(const short4*)((const short*)(h + (size_t)s * 512) + lt * 4);
            const __hip_bfloat16* sb = (const __hip_bfloat16*)&sv;
#pragma unroll
            for (int j = 0; j < 4; j++) {
                float p = breg[j];
                p = fmaf(e0.x, wreg[j][0], p);  p = fmaf(e0.y, wreg[j][1], p);
                p = fmaf(e0.z, wreg[j][2], p);  p = fmaf(e0.w, wreg[j][3], p);
                p = fmaf(e1.x, wreg[j][4], p);  p = fmaf(e1.y, wreg[j][5], p);
                p = fmaf(e1.z, wreg[j][6], p);  p = fmaf(e1.w, wreg[j][7], p);
                p = fmaf(e2v.x, wreg[j][8], p); p = fmaf(e2v.y, wreg[j][9], p);
                p = fmaf(e2v.z, wreg[j][10], p);p = fmaf(e2v.w, wreg[j][11], p);
                p = fmaf(e3.x, wreg[j][12], p); p = fmaf(e3.y, wreg[j][13], p);
                p = fmaf(e3.z, wreg[j][14], p); p = fmaf(e3.w, wreg[j][15], p);
                acc[j] += fmaxf(__bfloat162float(sb[j]) + p, 0.f);
            }
        }
        __hip_bfloat16 o[4];
#pragma unroll
        for (int j = 0; j < 4; j++) o[j] = __float2bfloat16(acc[j]);
        *(short4*)((short*)(a2 + (size_t)(n - n0) * 512) + lt * 4) = *(const short4*)o;
    }
}

// ---------------- MFMA GEMM: C[M,N] = A[M,K](bf16) @ B^T[N,K](bf16) ----------
#define ASTR 40
template <int MODE>
__global__ __launch_bounds__(256, 2) void mfma_gemm(
    const __hip_bfloat16* __restrict__ A, const __hip_bfloat16* __restrict__ Bhi,
    int M, int K, int N, const float* __restrict__ bias, const float* __restrict__ bng,
    const float* __restrict__ bnb, const int* __restrict__ batch,
    float* __restrict__ psum, __hip_bfloat16* __restrict__ Cout) {
    __shared__ short As[128 * ASTR];
    __shared__ short Bh[128 * ASTR];
    int r0 = blockIdx.x * 128;
    int n0 = blockIdx.y * 128;
    int tid = threadIdx.x;
    int lane = tid & 63;
    int wm = ((tid >> 6) >> 1) * 64, wn = ((tid >> 6) & 1) * 64;

    f32x4 acc[4][4];
#pragma unroll
    for (int i = 0; i < 4; i++)
#pragma unroll
        for (int j = 0; j < 4; j++) acc[i][j] = (f32x4){0.f, 0.f, 0.f, 0.f};

    for (int k0 = 0; k0 < K; k0 += 32) {
        __syncthreads();
#pragma unroll
        for (int j = 0; j < 2; j++) {
            int i = tid + j * 256;
            int row = i >> 2, cb = i & 3;
            int grow = r0 + row;
            if (grow >= M) grow = M - 1;
            *(int4*)(As + row * ASTR + cb * 8) =
                *(const int4*)(A + (size_t)grow * K + k0 + cb * 8);
        }
#pragma unroll
        for (int j = 0; j < 2; j++) {
            int i = tid + j * 256;
            int row = i >> 2, cb = i & 3;
            *(int4*)(Bh + row * ASTR + cb * 8) =
                *(const int4*)(Bhi + (size_t)(n0 + row) * K + k0 + cb * 8);
        }
        __syncthreads();
        int fi = lane & 15, kb = (lane >> 4) * 8;
        bf16x8 af[4], bhf[4];
#pragma unroll
        for (int mi = 0; mi < 4; mi++)
            af[mi] = *(const bf16x8*)(As + (wm + mi * 16 + fi) * ASTR + kb);
#pragma unroll
        for (int ni = 0; ni < 4; ni++)
            bhf[ni] = *(const bf16x8*)(Bh + (wn + ni * 16 + fi) * ASTR + kb);
#pragma unroll
        for (int mi = 0; mi < 4; mi++)
#pragma unroll
            for (int ni = 0; ni < 4; ni++)
                acc[mi][ni] = __builtin_amdgcn_mfma_f32_16x16x32_bf16(af[mi], bhf[ni],
                                                                     acc[mi][ni], 0, 0, 0);
    }
    int col_l = lane & 15, quad = lane >> 4;
#pragma unroll
    for (int mi = 0; mi < 4; mi++) {
        int rbase = r0 + wm + mi * 16 + quad * 4;
#pragma unroll
        for (int ni = 0; ni < 4; ni++) {
            int gcol = n0 + wn + ni * 16 + col_l;
            if (MODE == 0) {
                float b0 = bias[gcol];
#pragma unroll
                for (int reg = 0; reg < 4; reg++) {
                    int grow = rbase + reg;
                    if (grow < M)
                        Cout[(size_t)grow * N + gcol] = __float2bfloat16(acc[mi][ni][reg] + b0);
                }
            } else {
                float b0 = bias[gcol], g0 = bng[gcol], bb0 = bnb[gcol];
                float vv[4];
#pragma unroll
                for (int reg = 0; reg < 4; reg++)
                    vv[reg] = fmaxf(fmaf((acc[mi][ni][reg] + b0) * bn_inv(), g0, bb0), 0.f);
                if (MODE == 1) {
#pragma unroll
                    for (int reg = 0; reg < 4; reg++) {
                        int grow = rbase + reg;
                        if (grow < M) Cout[(size_t)grow * 512 + gcol] = __float2bfloat16(vv[reg]);
                    }
                } else {
                    if (rbase + 3 < M && batch[rbase] == batch[rbase + 3]) {
                        atomicAdd(&psum[(size_t)batch[rbase] * 512 + gcol],
                                  (vv[0] + vv[1]) + (vv[2] + vv[3]));
                    } else {
#pragma unroll
                        for (int reg = 0; reg < 4; reg++) {
                            int grow = rbase + reg;
                            if (grow < M)
                                atomicAdd(&psum[(size_t)batch[grow] * 512 + gcol], vv[reg]);
                        }
                    }
                }
            }
        }
    }
}

// ---------------- node counts per graph --------------------------------------
__global__ void count_nodes(const int* __restrict__ batch, float* __restrict__ cnt) {
    int i = blockIdx.x * 256 + threadIdx.x;
    if (i < N_NODESC) atomicAdd(&cnt[batch[i]], 1.0f);
}

// ---------------- finalize pool + assemble xn [B,7,512] bf16 -----------------
__global__ void build_xn(const float* __restrict__ psum, const float* __restrict__ cnt,
                         const float* __restrict__ ecfp, const float* __restrict__ topo,
                         const float* __restrict__ maccs, const float* __restrict__ estate,
                         const float* __restrict__ rdkit2d, const float* __restrict__ phar2d,
                         __hip_bfloat16* __restrict__ xn) {
    int i = blockIdx.x * 256 + threadIdx.x;
    if (i >= BG * 512) return;
    int bidx = i >> 9, c = i & 511;
    float cv = fmaxf(cnt[bidx], 1.0f);
    __hip_bfloat16* o = xn + (size_t)bidx * 7 * 512;
    o[c] = __float2bfloat16(psum[i] / cv);
    o[512 + c] = __float2bfloat16(ecfp[i]);
    o[2 * 512 + c] = __float2bfloat16(topo[i]);
    o[3 * 512 + c] = __float2bfloat16(maccs[i]);
    o[4 * 512 + c] = __float2bfloat16(estate[i]);
    o[5 * 512 + c] = __float2bfloat16(rdkit2d[i]);
    o[6 * 512 + c] = __float2bfloat16(phar2d[i]);
}

// ---------------- GAT attention + aggregate + bn + relu (1 block/graph) ------
__global__ void gat_attn(const __hip_bfloat16* __restrict__ gl,
                         const __hip_bfloat16* __restrict__ gr,
                         const float* __restrict__ att, const float* __restrict__ bias,
                         const float* __restrict__ bng, const float* __restrict__ bnb,
                         __hip_bfloat16* __restrict__ zout) {
    int b = blockIdx.x;
    int tid = threadIdx.x;
    int wave = tid >> 6, lane = tid & 63;
    __shared__ float logits[13][4];
    __shared__ float alpha[13][4];
    const size_t base = (size_t)b * 7 * 4 * 512;
    for (int p = wave; p < 52; p += 4) {
        int e = p >> 2, hh = p & 3;
        int se = (e < 7) ? 0 : (e - 6);
        int de = (e < 6) ? (e + 1) : ((e == 6) ? 0 : (e - 6));
        const __hip_bfloat16* glp = gl + base + (size_t)(se * 4 + hh) * 512;
        const __hip_bfloat16* grp = gr + base + (size_t)(de * 4 + hh) * 512;
        const float* ap = att + hh * 512;
        float s = 0.f;
#pragma unroll
        for (int j = 0; j < 8; j++) {
            int c = lane + j * 64;
            float v = __bfloat162float(glp[c]) + __bfloat162float(grp[c]);
            v = (v >= 0.f) ? v : 0.2f * v;
            s = fmaf(v, ap[c], s);
        }
#pragma unroll
        for (int off = 32; off; off >>= 1) s += __shfl_down(s, off);
        if (lane == 0) logits[e][hh] = s;
    }
    __syncthreads();
    if (tid < 24) {
        int n = 1 + (tid >> 2), hh = tid & 3;
        float la = logits[n - 1][hh], lb = logits[6 + n][hh];
        float m = fmaxf(la, lb);
        float ea = __expf(la - m), eb = __expf(lb - m);
        float inv = 1.f / (ea + eb);
        alpha[n - 1][hh] = ea * inv;
        alpha[6 + n][hh] = eb * inv;
    } else if (tid < 28) {
        alpha[6][tid & 3] = 1.f;
    }
    __syncthreads();
    for (int i = tid; i < 7 * 512; i += 256) {
        int n = i >> 9, c = i & 511;
        float v = 0.f;
        if (n == 0) {
#pragma unroll
            for (int hh = 0; hh < 4; hh++)
                v = fmaf(alpha[6][hh], __bfloat162float(gl[base + (size_t)hh * 512 + c]), v);
        } else {
#pragma unroll
            for (int hh = 0; hh < 4; hh++) {
                v = fmaf(alpha[n - 1][hh], __bfloat162float(gl[base + (size_t)hh * 512 + c]), v);
                v = fmaf(alpha[6 + n][hh],
                         __bfloat162float(gl[base + (size_t)(n * 4 + hh) * 512 + c]), v);
            }
        }
        v = fmaf(v, 0.25f, bias[c]);
        v = fmaf(v * bn_inv(), bng[c], bnb[c]);
        zout[(size_t)b * 7 * 512 + i] = __float2bfloat16(fmaxf(v, 0.f));
    }
}

// ---------------- final fc ----------------------------------------------------
__global__ void final_fc(const __hip_bfloat16* __restrict__ z, const float* __restrict__ fcW,
                         const float* __restrict__ fcb, float* __restrict__ out) {
    int b = blockIdx.x * 4 + (threadIdx.x >> 6);
    int lane = threadIdx.x & 63;
    if (b >= BG) return;
    const __hip_bfloat16* row = z + (size_t)b * 7 * 512;
    float s = 0.f;
#pragma unroll
    for (int j = 0; j < 8; j++)
        s = fmaf(__bfloat162float(row[lane + j * 64]), fcW[lane + j * 64], s);
#pragma unroll
    for (int off = 32; off; off >>= 1) s += __shfl_down(s, off);
    if (lane == 0) out[b] = s + fcb[0];
}

extern "C" void kernel_launch(void* const* d_in, const int* in_sizes, int n_in,
                              void* d_out, int out_size, void* d_ws, size_t ws_size,
                              hipStream_t stream) {
    const float* x = (const float*)d_in[0];
    const int* eidx = (const int*)d_in[1];
    const float* eattr = (const float*)d_in[2];
    const int* batch = (const int*)d_in[3];
    const float* ecfp = (const float*)d_in[4];
    const float* topo = (const float*)d_in[5];
    const float* maccs = (const float*)d_in[6];
    const float* estate = (const float*)d_in[7];
    const float* rdkit2d = (const float*)d_in[8];
    const float* phar2d = (const float*)d_in[9];
    const float* g1_W = (const float*)d_in[10];
    const float* g1_b = (const float*)d_in[11];
    const float* e1_W = (const float*)d_in[12];
    const float* e1_b = (const float*)d_in[13];
    const float* bn1_g = (const float*)d_in[14];
    const float* bn1_b = (const float*)d_in[15];
    const float* g2_W = (const float*)d_in[16];
    const float* g2_b = (const float*)d_in[17];
    const float* e2_W = (const float*)d_in[18];
    const float* e2_b = (const float*)d_in[19];
    const float* bn2_g = (const float*)d_in[20];
    const float* bn2_b = (const float*)d_in[21];
    const float* gat1_Wl = (const float*)d_in[22];
    const float* gat1_bl = (const float*)d_in[23];
    const float* gat1_Wr = (const float*)d_in[24];
    const float* gat1_br = (const float*)d_in[25];
    const float* gat1_att = (const float*)d_in[26];
    const float* gat1_bias = (const float*)d_in[27];
    const float* bn3_g = (const float*)d_in[28];
    const float* bn3_b = (const float*)d_in[29];
    const float* gat2_Wl = (const float*)d_in[30];
    const float* gat2_bl = (const float*)d_in[31];
    const float* gat2_Wr = (const float*)d_in[32];
    const float* gat2_br = (const float*)d_in[33];
    const float* gat2_att = (const float*)d_in[34];
    const float* gat2_bias = (const float*)d_in[35];
    const float* bn4_g = (const float*)d_in[36];
    const float* bn4_b = (const float*)d_in[37];
    const float* fc_W = (const float*)d_in[38];
    const float* fc_b = (const float*)d_in[39];
    float* out = (float*)d_out;

    // ---- workspace layout (byte offsets; total 194,682,880 — proven fit) ----
    const size_t NEEDED = 194682880ull;
    if (ws_size < NEEDED) {
        zero_out<<<(BG + 255) / 256, 256, 0, stream>>>(out, BG);
        return;
    }
    char* w = (char*)d_ws;
    __hip_bfloat16* H = (__hip_bfloat16*)w;
    __hip_bfloat16* GL = (__hip_bfloat16*)w;
    __hip_bfloat16* Z1B = (__hip_bfloat16*)(w + 58720256);
    __hip_bfloat16* GW1L = (__hip_bfloat16*)(w + 73400320);
    __hip_bfloat16* GW1R = GW1L + 2048 * 512;
    __hip_bfloat16* GW2L = GW1R + 2048 * 512;
    __hip_bfloat16* GW2R = GW2L + 2048 * 512;

    __hip_bfloat16* A2 = (__hip_bfloat16*)(w + 102400000);
    __hip_bfloat16* GR = (__hip_bfloat16*)(w + 102400000);

    char* C = w + 161120256;
    __hip_bfloat16* XIN = (__hip_bfloat16*)C;
    __hip_bfloat16* XNB = (__hip_bfloat16*)C;
    __hip_bfloat16* Z2B = (__hip_bfloat16*)(C + 14680064);
    int* ROWPTR = (int*)(C + 14680064);
    int* CURSOR = (int*)(C + 15080192);
    int* EID = (int*)(C + 15480320);
    int* DEG = (int*)(C + 16280320);
    __hip_bfloat16* G1W = (__hip_bfloat16*)(C + 16680320);
    __hip_bfloat16* G2W = (__hip_bfloat16*)(C + 16745856);
    int* BSUM = (int*)(C + 17270144);

    float* PS = (float*)(w + 190480384);
    float* PC = (float*)(w + 194674688);

    const int* src = eidx;
    const int* dst = eidx + N_EDGESC;

    // ---- CSR build ----
    zero_int<<<(N_NODESC + 255) / 256, 256, 0, stream>>>(DEG, N_NODESC);
    zero_f4<<<(BG * 512 / 4 + 255) / 256, 256, 0, stream>>>((float4*)PS, BG * 512 / 4);
    zero_f4<<<(BG / 4 + 255) / 256, 256, 0, stream>>>((float4*)PC, BG / 4);
    hist_dst<<<(N_EDGESC + 255) / 256, 256, 0, stream>>>(dst, DEG);
    const int NB = (N_NODESC + 1023) / 1024;  // 98
    scan_bsums<<<NB, 256, 0, stream>>>(DEG, BSUM, N_NODESC);
    scan_top<<<1, 64, 0, stream>>>(BSUM, NB, ROWPTR + N_NODESC);
    scan_final<<<NB, 256, 0, stream>>>(DEG, BSUM, ROWPTR, CURSOR, N_NODESC);
    scatter_eid<<<(N_EDGESC + 255) / 256, 256, 0, stream>>>(dst, CURSOR, EID);

    // ---- GINE weight prep ----
    transpose_w<<<dim3(1, 8), 256, 0, stream>>>(g1_W, G1W, 64, 512);
    transpose_w<<<dim3(8, 8), 256, 0, stream>>>(g2_W, G2W, 512, 512);

    // ---- GINE1 ----
    gine1_gather<<<(N_NODESC + 4 * G1_NPW - 1) / (4 * G1_NPW), 256, 0, stream>>>(
        x, src, eattr, e1_W, e1_b, ROWPTR, EID, XIN);
    mfma_gemm<1><<<dim3((N_NODESC + 127) / 128, 4), 256, 0, stream>>>(
        XIN, G1W, N_NODESC, 64, 512, g1_b, bn1_g, bn1_b, nullptr, nullptr, H);
    count_nodes<<<(N_NODESC + 255) / 256, 256, 0, stream>>>(batch, PC);

    // ---- GINE2: 2 chunks of 50k nodes ----
    for (int c0n = 0; c0n < N_NODESC; c0n += 50000) {
        int c1n = c0n + 50000;
        int rows = 50000;
        gine2_gather<<<(rows + G2_NPB - 1) / G2_NPB, 256, 0, stream>>>(
            H, src, eattr, e2_W, e2_b, ROWPTR, EID, A2, c0n, c1n);
        mfma_gemm<2><<<dim3((rows + 127) / 128, 4), 256, 0, stream>>>(
            A2, G2W, rows, 512, 512, g2_b, bn2_g, bn2_b, batch + c0n, PS, nullptr);
    }

    // ---- GAT weight prep (H dead) ----
    transpose_w<<<dim3(8, 32), 256, 0, stream>>>(gat1_Wl, GW1L, 512, 2048);
    transpose_w<<<dim3(8, 32), 256, 0, stream>>>(gat1_Wr, GW1R, 512, 2048);
    transpose_w<<<dim3(8, 32), 256, 0, stream>>>(gat2_Wl, GW2L, 512, 2048);
    transpose_w<<<dim3(8, 32), 256, 0, stream>>>(gat2_Wr, GW2R, 512, 2048);

    // ---- pool -> xn ----
    build_xn<<<(BG * 512) / 256, 256, 0, stream>>>(PS, PC, ecfp, topo, maccs, estate,
                                                   rdkit2d, phar2d, XNB);
    // ---- GAT layer 1 ----
    const int MGAT = BG * 7;  // 14336
    dim3 ggrid(MGAT / 128, 16);
    mfma_gemm<0><<<ggrid, 256, 0, stream>>>(XNB, GW1L, MGAT, 512, 2048, gat1_bl,
                                            nullptr, nullptr, nullptr, nullptr, GL);
    mfma_gemm<0><<<ggrid, 256, 0, stream>>>(XNB, GW1R, MGAT, 512, 2048, gat1_br,
                                            nullptr, nullptr, nullptr, nullptr, GR);
    gat_attn<<<BG, 256, 0, stream>>>(GL, GR, gat1_att, gat1_bias, bn3_g, bn3_b, Z1B);
    // ---- GAT layer 2 ----
    mfma_gemm<0><<<ggrid, 256, 0, stream>>>(Z1B, GW2L, MGAT, 512, 2048, gat2_bl,
                                            nullptr, nullptr, nullptr, nullptr, GL);
    mfma_gemm<0><<<ggrid, 256, 0, stream>>>(Z1B, GW2R, MGAT, 512, 2048, gat2_br,
                                            nullptr, nullptr, nullptr, nullptr, GR);
    gat_attn<<<BG, 256, 0, stream>>>(GL, GR, gat2_att, gat2_bias, bn4_g, bn4_b, Z2B);
    // ---- final fc ----
    final_fc<<<BG / 4, 256, 0, stream>>>(Z2B, fc_W, fc_b, out);
}

// Round 6
// 1051.519 us; speedup vs baseline: 3.4999x; 1.0178x over previous
//
#include <hip/hip_runtime.h>
#include <hip/hip_bf16.h>

#define N_NODESC 100000
#define N_EDGESC 200000
#define BG 2048
#define NDIM 64
#define EDIM 16

typedef __bf16 bf16x8 __attribute__((ext_vector_type(8)));
typedef float f32x4 __attribute__((ext_vector_type(4)));

static __device__ __forceinline__ float bn_inv() { return 0.9999950000374997f; }

// ---------------- zero fills --------------------------------------------------
__global__ void zero_f4(float4* __restrict__ p, int n4) {
    int i = blockIdx.x * 256 + threadIdx.x;
    if (i < n4) p[i] = make_float4(0.f, 0.f, 0.f, 0.f);
}
__global__ void zero_int(int* __restrict__ p, int n) {
    int i = blockIdx.x * 256 + threadIdx.x;
    if (i < n) p[i] = 0;
}
__global__ void zero_out(float* __restrict__ p, int n) {
    int i = blockIdx.x * 256 + threadIdx.x;
    if (i < n) p[i] = 0.f;
}

// ---------------- CSR build: histogram -> scan -> scatter --------------------
__global__ void hist_dst(const int* __restrict__ dst, int* __restrict__ deg) {
    int i = blockIdx.x * 256 + threadIdx.x;
    if (i < N_EDGESC) atomicAdd(&deg[dst[i]], 1);
}
__global__ void scan_bsums(const int* __restrict__ deg, int* __restrict__ bsum, int n) {
    __shared__ int ls[256];
    int b = blockIdx.x, t = threadIdx.x;
    int s = 0;
#pragma unroll
    for (int j = 0; j < 4; j++) {
        int i = b * 1024 + t * 4 + j;
        if (i < n) s += deg[i];
    }
    ls[t] = s;
    __syncthreads();
    for (int off = 128; off; off >>= 1) {
        if (t < off) ls[t] += ls[t + off];
        __syncthreads();
    }
    if (t == 0) bsum[b] = ls[0];
}
__global__ void scan_top(int* __restrict__ bsum, int nb, int* __restrict__ total) {
    if (threadIdx.x == 0) {
        int acc = 0;
        for (int i = 0; i < nb; i++) { int v = bsum[i]; bsum[i] = acc; acc += v; }
        *total = acc;
    }
}
__global__ void scan_final(const int* __restrict__ deg, const int* __restrict__ bsum,
                           int* __restrict__ rowptr, int* __restrict__ cursor, int n) {
    __shared__ int ls[256];
    int b = blockIdx.x, t = threadIdx.x;
    int v[4], s = 0;
#pragma unroll
    for (int j = 0; j < 4; j++) {
        int i = b * 1024 + t * 4 + j;
        v[j] = (i < n) ? deg[i] : 0;
        s += v[j];
    }
    ls[t] = s;
    __syncthreads();
    int run = s;
    for (int off = 1; off < 256; off <<= 1) {
        int add = (t >= off) ? ls[t - off] : 0;
        __syncthreads();
        ls[t] += add;
        __syncthreads();
    }
    int excl = ls[t] - run + bsum[b];
#pragma unroll
    for (int j = 0; j < 4; j++) {
        int i = b * 1024 + t * 4 + j;
        if (i < n) { rowptr[i] = excl; cursor[i] = excl; excl += v[j]; }
    }
}
__global__ void scatter_eid(const int* __restrict__ dst, int* __restrict__ cursor,
                            int* __restrict__ eid) {
    int e = blockIdx.x * 256 + threadIdx.x;
    if (e < N_EDGESC) {
        int p = atomicAdd(&cursor[dst[e]], 1);
        eid[p] = e;
    }
}

// ---------------- W [K][N] f32 -> bf16 [N][K] --------------------------------
__global__ void transpose_w(const float* __restrict__ W, __hip_bfloat16* __restrict__ hi,
                            int K, int N) {
    __shared__ float t[64][65];
    int k0 = blockIdx.x * 64, n0 = blockIdx.y * 64;
    int tid = threadIdx.x, tx = tid & 63, ty = tid >> 6;
    for (int r = ty; r < 64; r += 4) t[r][tx] = W[(size_t)(k0 + r) * N + n0 + tx];
    __syncthreads();
    for (int r = ty; r < 64; r += 4)
        hi[(size_t)(n0 + r) * K + k0 + tx] = __float2bfloat16(t[tx][r]);
}

__global__ void concat_bias(const float* __restrict__ a, const float* __restrict__ b,
                            float* __restrict__ o) {
    int i = blockIdx.x * 256 + threadIdx.x;
    if (i < 2048) { o[i] = a[i]; o[2048 + i] = b[i]; }
}

// ---------------- GINE1 gather -----------------------------------------------
#define G1_NPW 8
__global__ __launch_bounds__(256, 2) void gine1_gather(
    const float* __restrict__ x, const int* __restrict__ srcv, const float* __restrict__ ea,
    const float* __restrict__ e1W, const float* __restrict__ e1b,
    const int* __restrict__ rowptr, const int* __restrict__ eid,
    __hip_bfloat16* __restrict__ xin) {
    int tid = threadIdx.x;
    int wave = tid >> 6, lane = tid & 63;
    float wreg[16];
#pragma unroll
    for (int k = 0; k < 16; k++) wreg[k] = e1W[k * 64 + lane];
    float bb = e1b[lane];
    int nbase = (blockIdx.x * 4 + wave) * G1_NPW;
#pragma unroll 1
    for (int it = 0; it < G1_NPW; it++) {
        int n = nbase + it;
        if (n >= N_NODESC) return;
        float acc = x[(size_t)n * 64 + lane];
        int beg = rowptr[n], end = rowptr[n + 1];
        for (int idx = beg; idx < end; idx++) {
            int e = eid[idx], s = srcv[e];
            const float4* ef = (const float4*)(ea + (size_t)e * 16);
            float4 e0 = ef[0], e1 = ef[1], e2 = ef[2], e3 = ef[3];
            float p = bb;
            p = fmaf(e0.x, wreg[0], p);  p = fmaf(e0.y, wreg[1], p);
            p = fmaf(e0.z, wreg[2], p);  p = fmaf(e0.w, wreg[3], p);
            p = fmaf(e1.x, wreg[4], p);  p = fmaf(e1.y, wreg[5], p);
            p = fmaf(e1.z, wreg[6], p);  p = fmaf(e1.w, wreg[7], p);
            p = fmaf(e2.x, wreg[8], p);  p = fmaf(e2.y, wreg[9], p);
            p = fmaf(e2.z, wreg[10], p); p = fmaf(e2.w, wreg[11], p);
            p = fmaf(e3.x, wreg[12], p); p = fmaf(e3.y, wreg[13], p);
            p = fmaf(e3.z, wreg[14], p); p = fmaf(e3.w, wreg[15], p);
            acc += fmaxf(x[(size_t)s * 64 + lane] + p, 0.f);
        }
        xin[(size_t)n * 64 + lane] = __float2bfloat16(acc);
    }
}

// ---------------- GINE2 gather -----------------------------------------------
#define G2_NPB 16
__global__ __launch_bounds__(256, 2) void gine2_gather(
    const __hip_bfloat16* __restrict__ h, const int* __restrict__ srcv,
    const float* __restrict__ ea, const float* __restrict__ e2W,
    const float* __restrict__ e2b, const int* __restrict__ rowptr,
    const int* __restrict__ eid, __hip_bfloat16* __restrict__ a2, int n0, int n1) {
    int tid = threadIdx.x;
    int half = tid >> 7, lt = tid & 127;
    float wreg[4][16], breg[4];
#pragma unroll
    for (int j = 0; j < 4; j++) {
        int c = lt * 4 + j;
        breg[j] = e2b[c];
#pragma unroll
        for (int k = 0; k < 16; k++) wreg[j][k] = e2W[k * 512 + c];
    }
    int nbase = n0 + blockIdx.x * G2_NPB + half;
#pragma unroll 1
    for (int it = 0; it < G2_NPB / 2; it++) {
        int n = nbase + it * 2;
        if (n >= n1) return;
        short4 hv = *(const short4*)((const short*)(h + (size_t)n * 512) + lt * 4);
        const __hip_bfloat16* hb = (const __hip_bfloat16*)&hv;
        float acc[4];
#pragma unroll
        for (int j = 0; j < 4; j++) acc[j] = __bfloat162float(hb[j]);
        int beg = rowptr[n], end = rowptr[n + 1];
        for (int idx = beg; idx < end; idx++) {
            int e = eid[idx], s = srcv[e];
            const float4* ef = (const float4*)(ea + (size_t)e * 16);
            float4 e0 = ef[0], e1 = ef[1], e2v = ef[2], e3 = ef[3];
            short4 sv = *(const short4*)((const short*)(h + (size_t)s * 512) + lt * 4);
            const __hip_bfloat16* sb = (const __hip_bfloat16*)&sv;
#pragma unroll
            for (int j = 0; j < 4; j++) {
                float p = breg[j];
                p = fmaf(e0.x, wreg[j][0], p);  p = fmaf(e0.y, wreg[j][1], p);
                p = fmaf(e0.z, wreg[j][2], p);  p = fmaf(e0.w, wreg[j][3], p);
                p = fmaf(e1.x, wreg[j][4], p);  p = fmaf(e1.y, wreg[j][5], p);
                p = fmaf(e1.z, wreg[j][6], p);  p = fmaf(e1.w, wreg[j][7], p);
                p = fmaf(e2v.x, wreg[j][8], p); p = fmaf(e2v.y, wreg[j][9], p);
                p = fmaf(e2v.z, wreg[j][10], p);p = fmaf(e2v.w, wreg[j][11], p);
                p = fmaf(e3.x, wreg[j][12], p); p = fmaf(e3.y, wreg[j][13], p);
                p = fmaf(e3.z, wreg[j][14], p); p = fmaf(e3.w, wreg[j][15], p);
                acc[j] += fmaxf(__bfloat162float(sb[j]) + p, 0.f);
            }
        }
        __hip_bfloat16 o[4];
#pragma unroll
        for (int j = 0; j < 4; j++) o[j] = __float2bfloat16(acc[j]);
        *(short4*)((short*)(a2 + (size_t)(n - n0) * 512) + lt * 4) = *(const short4*)o;
    }
}

// ---------------- MFMA GEMM: C[M,N] = A[M,K](bf16) @ B^T[N,K](bf16) ----------
// GRID: x = col-tile (FAST -> concurrent blocks share A rows), y = row-tile.
#define ASTR 40
template <int MODE>
__global__ __launch_bounds__(256, 2) void mfma_gemm(
    const __hip_bfloat16* __restrict__ A, const __hip_bfloat16* __restrict__ Bhi,
    int M, int K, int N, const float* __restrict__ bias, const float* __restrict__ bng,
    const float* __restrict__ bnb, const int* __restrict__ batch,
    float* __restrict__ psum, __hip_bfloat16* __restrict__ Cout) {
    __shared__ short As[128 * ASTR];
    __shared__ short Bh[128 * ASTR];
    int r0 = blockIdx.y * 128;
    int n0 = blockIdx.x * 128;
    int tid = threadIdx.x;
    int lane = tid & 63;
    int wm = ((tid >> 6) >> 1) * 64, wn = ((tid >> 6) & 1) * 64;

    f32x4 acc[4][4];
#pragma unroll
    for (int i = 0; i < 4; i++)
#pragma unroll
        for (int j = 0; j < 4; j++) acc[i][j] = (f32x4){0.f, 0.f, 0.f, 0.f};

    for (int k0 = 0; k0 < K; k0 += 32) {
        __syncthreads();
#pragma unroll
        for (int j = 0; j < 2; j++) {
            int i = tid + j * 256;
            int row = i >> 2, cb = i & 3;
            int grow = r0 + row;
            if (grow >= M) grow = M - 1;
            *(int4*)(As + row * ASTR + cb * 8) =
                *(const int4*)(A + (size_t)grow * K + k0 + cb * 8);
        }
#pragma unroll
        for (int j = 0; j < 2; j++) {
            int i = tid + j * 256;
            int row = i >> 2, cb = i & 3;
            *(int4*)(Bh + row * ASTR + cb * 8) =
                *(const int4*)(Bhi + (size_t)(n0 + row) * K + k0 + cb * 8);
        }
        __syncthreads();
        int fi = lane & 15, kb = (lane >> 4) * 8;
        bf16x8 af[4], bhf[4];
#pragma unroll
        for (int mi = 0; mi < 4; mi++)
            af[mi] = *(const bf16x8*)(As + (wm + mi * 16 + fi) * ASTR + kb);
#pragma unroll
        for (int ni = 0; ni < 4; ni++)
            bhf[ni] = *(const bf16x8*)(Bh + (wn + ni * 16 + fi) * ASTR + kb);
#pragma unroll
        for (int mi = 0; mi < 4; mi++)
#pragma unroll
            for (int ni = 0; ni < 4; ni++)
                acc[mi][ni] = __builtin_amdgcn_mfma_f32_16x16x32_bf16(af[mi], bhf[ni],
                                                                     acc[mi][ni], 0, 0, 0);
    }
    int col_l = lane & 15, quad = lane >> 4;
#pragma unroll
    for (int mi = 0; mi < 4; mi++) {
        int rbase = r0 + wm + mi * 16 + quad * 4;
#pragma unroll
        for (int ni = 0; ni < 4; ni++) {
            int gcol = n0 + wn + ni * 16 + col_l;
            if (MODE == 0) {
                float b0 = bias[gcol];
#pragma unroll
                for (int reg = 0; reg < 4; reg++) {
                    int grow = rbase + reg;
                    if (grow < M)
                        Cout[(size_t)grow * N + gcol] = __float2bfloat16(acc[mi][ni][reg] + b0);
                }
            } else {
                float b0 = bias[gcol], g0 = bng[gcol], bb0 = bnb[gcol];
                float vv[4];
#pragma unroll
                for (int reg = 0; reg < 4; reg++)
                    vv[reg] = fmaxf(fmaf((acc[mi][ni][reg] + b0) * bn_inv(), g0, bb0), 0.f);
                if (MODE == 1) {
#pragma unroll
                    for (int reg = 0; reg < 4; reg++) {
                        int grow = rbase + reg;
                        if (grow < M) Cout[(size_t)grow * 512 + gcol] = __float2bfloat16(vv[reg]);
                    }
                } else {
                    if (rbase + 3 < M && batch[rbase] == batch[rbase + 3]) {
                        atomicAdd(&psum[(size_t)batch[rbase] * 512 + gcol],
                                  (vv[0] + vv[1]) + (vv[2] + vv[3]));
                    } else {
#pragma unroll
                        for (int reg = 0; reg < 4; reg++) {
                            int grow = rbase + reg;
                            if (grow < M)
                                atomicAdd(&psum[(size_t)batch[grow] * 512 + gcol], vv[reg]);
                        }
                    }
                }
            }
        }
    }
}

// ---------------- node counts per graph --------------------------------------
__global__ void count_nodes(const int* __restrict__ batch, float* __restrict__ cnt) {
    int i = blockIdx.x * 256 + threadIdx.x;
    if (i < N_NODESC) atomicAdd(&cnt[batch[i]], 1.0f);
}

// ---------------- finalize pool + assemble xn [B,7,512] bf16 -----------------
__global__ void build_xn(const float* __restrict__ psum, const float* __restrict__ cnt,
                         const float* __restrict__ ecfp, const float* __restrict__ topo,
                         const float* __restrict__ maccs, const float* __restrict__ estate,
                         const float* __restrict__ rdkit2d, const float* __restrict__ phar2d,
                         __hip_bfloat16* __restrict__ xn) {
    int i = blockIdx.x * 256 + threadIdx.x;
    if (i >= BG * 512) return;
    int bidx = i >> 9, c = i & 511;
    float cv = fmaxf(cnt[bidx], 1.0f);
    __hip_bfloat16* o = xn + (size_t)bidx * 7 * 512;
    o[c] = __float2bfloat16(psum[i] / cv);
    o[512 + c] = __float2bfloat16(ecfp[i]);
    o[2 * 512 + c] = __float2bfloat16(topo[i]);
    o[3 * 512 + c] = __float2bfloat16(maccs[i]);
    o[4 * 512 + c] = __float2bfloat16(estate[i]);
    o[5 * 512 + c] = __float2bfloat16(rdkit2d[i]);
    o[6 * 512 + c] = __float2bfloat16(phar2d[i]);
}

// ---------------- GAT attention (fused gl|gr layout: C[B*7][4096]) -----------
// gl[node m][h][c] = cg[(b*7+m)*4096 + h*512 + c]; gr = same + 2048
__global__ void gat_attn(const __hip_bfloat16* __restrict__ cg,
                         const float* __restrict__ att, const float* __restrict__ bias,
                         const float* __restrict__ bng, const float* __restrict__ bnb,
                         __hip_bfloat16* __restrict__ zout) {
    int b = blockIdx.x;
    int tid = threadIdx.x;
    int wave = tid >> 6, lane = tid & 63;
    __shared__ float logits[13][4];
    __shared__ float alpha[13][4];
    const size_t base = (size_t)b * 7 * 4096;
    for (int p = wave; p < 52; p += 4) {
        int e = p >> 2, hh = p & 3;
        int se = (e < 7) ? 0 : (e - 6);
        int de = (e < 6) ? (e + 1) : ((e == 6) ? 0 : (e - 6));
        const __hip_bfloat16* glp = cg + base + (size_t)se * 4096 + hh * 512;
        const __hip_bfloat16* grp = cg + base + (size_t)de * 4096 + 2048 + hh * 512;
        const float* ap = att + hh * 512;
        float s = 0.f;
#pragma unroll
        for (int j = 0; j < 8; j++) {
            int c = lane + j * 64;
            float v = __bfloat162float(glp[c]) + __bfloat162float(grp[c]);
            v = (v >= 0.f) ? v : 0.2f * v;
            s = fmaf(v, ap[c], s);
        }
#pragma unroll
        for (int off = 32; off; off >>= 1) s += __shfl_down(s, off);
        if (lane == 0) logits[e][hh] = s;
    }
    __syncthreads();
    if (tid < 24) {
        int n = 1 + (tid >> 2), hh = tid & 3;
        float la = logits[n - 1][hh], lb = logits[6 + n][hh];
        float m = fmaxf(la, lb);
        float ea = __expf(la - m), eb = __expf(lb - m);
        float inv = 1.f / (ea + eb);
        alpha[n - 1][hh] = ea * inv;
        alpha[6 + n][hh] = eb * inv;
    } else if (tid < 28) {
        alpha[6][tid & 3] = 1.f;
    }
    __syncthreads();
    for (int i = tid; i < 7 * 512; i += 256) {
        int n = i >> 9, c = i & 511;
        float v = 0.f;
        if (n == 0) {
#pragma unroll
            for (int hh = 0; hh < 4; hh++)
                v = fmaf(alpha[6][hh],
                         __bfloat162float(cg[base + (size_t)hh * 512 + c]), v);
        } else {
#pragma unroll
            for (int hh = 0; hh < 4; hh++) {
                v = fmaf(alpha[n - 1][hh],
                         __bfloat162float(cg[base + (size_t)hh * 512 + c]), v);
                v = fmaf(alpha[6 + n][hh],
                         __bfloat162float(cg[base + (size_t)n * 4096 + hh * 512 + c]), v);
            }
        }
        v = fmaf(v, 0.25f, bias[c]);
        v = fmaf(v * bn_inv(), bng[c], bnb[c]);
        zout[(size_t)b * 7 * 512 + i] = __float2bfloat16(fmaxf(v, 0.f));
    }
}

// ---------------- final fc ----------------------------------------------------
__global__ void final_fc(const __hip_bfloat16* __restrict__ z, const float* __restrict__ fcW,
                         const float* __restrict__ fcb, float* __restrict__ out) {
    int b = blockIdx.x * 4 + (threadIdx.x >> 6);
    int lane = threadIdx.x & 63;
    if (b >= BG) return;
    const __hip_bfloat16* row = z + (size_t)b * 7 * 512;
    float s = 0.f;
#pragma unroll
    for (int j = 0; j < 8; j++)
        s = fmaf(__bfloat162float(row[lane + j * 64]), fcW[lane + j * 64], s);
#pragma unroll
    for (int off = 32; off; off >>= 1) s += __shfl_down(s, off);
    if (lane == 0) out[b] = s + fcb[0];
}

extern "C" void kernel_launch(void* const* d_in, const int* in_sizes, int n_in,
                              void* d_out, int out_size, void* d_ws, size_t ws_size,
                              hipStream_t stream) {
    const float* x = (const float*)d_in[0];
    const int* eidx = (const int*)d_in[1];
    const float* eattr = (const float*)d_in[2];
    const int* batch = (const int*)d_in[3];
    const float* ecfp = (const float*)d_in[4];
    const float* topo = (const float*)d_in[5];
    const float* maccs = (const float*)d_in[6];
    const float* estate = (const float*)d_in[7];
    const float* rdkit2d = (const float*)d_in[8];
    const float* phar2d = (const float*)d_in[9];
    const float* g1_W = (const float*)d_in[10];
    const float* g1_b = (const float*)d_in[11];
    const float* e1_W = (const float*)d_in[12];
    const float* e1_b = (const float*)d_in[13];
    const float* bn1_g = (const float*)d_in[14];
    const float* bn1_b = (const float*)d_in[15];
    const float* g2_W = (const float*)d_in[16];
    const float* g2_b = (const float*)d_in[17];
    const float* e2_W = (const float*)d_in[18];
    const float* e2_b = (const float*)d_in[19];
    const float* bn2_g = (const float*)d_in[20];
    const float* bn2_b = (const float*)d_in[21];
    const float* gat1_Wl = (const float*)d_in[22];
    const float* gat1_bl = (const float*)d_in[23];
    const float* gat1_Wr = (const float*)d_in[24];
    const float* gat1_br = (const float*)d_in[25];
    const float* gat1_att = (const float*)d_in[26];
    const float* gat1_bias = (const float*)d_in[27];
    const float* bn3_g = (const float*)d_in[28];
    const float* bn3_b = (const float*)d_in[29];
    const float* gat2_Wl = (const float*)d_in[30];
    const float* gat2_bl = (const float*)d_in[31];
    const float* gat2_Wr = (const float*)d_in[32];
    const float* gat2_br = (const float*)d_in[33];
    const float* gat2_att = (const float*)d_in[34];
    const float* gat2_bias = (const float*)d_in[35];
    const float* bn4_g = (const float*)d_in[36];
    const float* bn4_b = (const float*)d_in[37];
    const float* fc_W = (const float*)d_in[38];
    const float* fc_b = (const float*)d_in[39];
    float* out = (float*)d_out;

    // ---- workspace layout (byte offsets; total 194,682,880 — proven fit) ----
    // GINE phase: H bf16 @0 (102,400,000); A2 bf16 @102,400,000 (51,200,000);
    //             XIN @161,120,256 (12,800,000); CSR+G1W/G2W inside Z2B slot.
    // GAT phase (H,A2 dead): CG bf16 [14336][4096] @0 (117,440,512);
    //   GW12 @117,440,512 (4,194,304); GW34 @121,634,816 (4,194,304);
    //   Z1B @125,829,120 (14,680,064); B12 @140,509,184 (16,384); B34 @140,525,568;
    //   XNB @161,120,256 (14,680,064); Z2B @175,800,320 (14,680,064).
    // PS @190,480,384 (4,194,304); PC @194,674,688 (8,192).
    const size_t NEEDED = 194682880ull;
    if (ws_size < NEEDED) {
        zero_out<<<(BG + 255) / 256, 256, 0, stream>>>(out, BG);
        return;
    }
    char* w = (char*)d_ws;
    __hip_bfloat16* H = (__hip_bfloat16*)w;
    __hip_bfloat16* CG = (__hip_bfloat16*)w;
    __hip_bfloat16* A2 = (__hip_bfloat16*)(w + 102400000);
    __hip_bfloat16* GW12 = (__hip_bfloat16*)(w + 117440512);
    __hip_bfloat16* GW34 = (__hip_bfloat16*)(w + 121634816);
    __hip_bfloat16* Z1B = (__hip_bfloat16*)(w + 125829120);
    float* B12 = (float*)(w + 140509184);
    float* B34 = (float*)(w + 140525568);

    char* C = w + 161120256;
    __hip_bfloat16* XIN = (__hip_bfloat16*)C;
    __hip_bfloat16* XNB = (__hip_bfloat16*)C;
    __hip_bfloat16* Z2B = (__hip_bfloat16*)(C + 14680064);
    int* ROWPTR = (int*)(C + 14680064);
    int* CURSOR = (int*)(C + 15080192);
    int* EID = (int*)(C + 15480320);
    int* DEG = (int*)(C + 16280320);
    __hip_bfloat16* G1W = (__hip_bfloat16*)(C + 16680320);
    __hip_bfloat16* G2W = (__hip_bfloat16*)(C + 16745856);
    int* BSUM = (int*)(C + 17270144);

    float* PS = (float*)(w + 190480384);
    float* PC = (float*)(w + 194674688);

    const int* src = eidx;
    const int* dst = eidx + N_EDGESC;

    // ---- CSR build ----
    zero_int<<<(N_NODESC + 255) / 256, 256, 0, stream>>>(DEG, N_NODESC);
    zero_f4<<<(BG * 512 / 4 + 255) / 256, 256, 0, stream>>>((float4*)PS, BG * 512 / 4);
    zero_f4<<<(BG / 4 + 255) / 256, 256, 0, stream>>>((float4*)PC, BG / 4);
    hist_dst<<<(N_EDGESC + 255) / 256, 256, 0, stream>>>(dst, DEG);
    const int NB = (N_NODESC + 1023) / 1024;  // 98
    scan_bsums<<<NB, 256, 0, stream>>>(DEG, BSUM, N_NODESC);
    scan_top<<<1, 64, 0, stream>>>(BSUM, NB, ROWPTR + N_NODESC);
    scan_final<<<NB, 256, 0, stream>>>(DEG, BSUM, ROWPTR, CURSOR, N_NODESC);
    scatter_eid<<<(N_EDGESC + 255) / 256, 256, 0, stream>>>(dst, CURSOR, EID);

    // ---- GINE weight prep ----
    transpose_w<<<dim3(1, 8), 256, 0, stream>>>(g1_W, G1W, 64, 512);
    transpose_w<<<dim3(8, 8), 256, 0, stream>>>(g2_W, G2W, 512, 512);

    // ---- GINE1 ----
    gine1_gather<<<(N_NODESC + 4 * G1_NPW - 1) / (4 * G1_NPW), 256, 0, stream>>>(
        x, src, eattr, e1_W, e1_b, ROWPTR, EID, XIN);
    mfma_gemm<1><<<dim3(4, (N_NODESC + 127) / 128), 256, 0, stream>>>(
        XIN, G1W, N_NODESC, 64, 512, g1_b, bn1_g, bn1_b, nullptr, nullptr, H);
    count_nodes<<<(N_NODESC + 255) / 256, 256, 0, stream>>>(batch, PC);

    // ---- GINE2: 2 chunks of 50k nodes ----
    for (int c0n = 0; c0n < N_NODESC; c0n += 50000) {
        int c1n = c0n + 50000;
        int rows = 50000;
        gine2_gather<<<(rows + G2_NPB - 1) / G2_NPB, 256, 0, stream>>>(
            H, src, eattr, e2_W, e2_b, ROWPTR, EID, A2, c0n, c1n);
        mfma_gemm<2><<<dim3(4, (rows + 127) / 128), 256, 0, stream>>>(
            A2, G2W, rows, 512, 512, g2_b, bn2_g, bn2_b, batch + c0n, PS, nullptr);
    }

    // ---- GAT weight prep (H and A2 dead) ----
    transpose_w<<<dim3(8, 32), 256, 0, stream>>>(gat1_Wl, GW12, 512, 2048);
    transpose_w<<<dim3(8, 32), 256, 0, stream>>>(gat1_Wr, GW12 + (size_t)2048 * 512, 512, 2048);
    transpose_w<<<dim3(8, 32), 256, 0, stream>>>(gat2_Wl, GW34, 512, 2048);
    transpose_w<<<dim3(8, 32), 256, 0, stream>>>(gat2_Wr, GW34 + (size_t)2048 * 512, 512, 2048);
    concat_bias<<<8, 256, 0, stream>>>(gat1_bl, gat1_br, B12);
    concat_bias<<<8, 256, 0, stream>>>(gat2_bl, gat2_br, B34);

    // ---- pool -> xn ----
    build_xn<<<(BG * 512) / 256, 256, 0, stream>>>(PS, PC, ecfp, topo, maccs, estate,
                                                   rdkit2d, phar2d, XNB);
    // ---- GAT layer 1 (fused L|R: N = 4096) ----
    const int MGAT = BG * 7;  // 14336
    dim3 ggrid(4096 / 128, MGAT / 128);
    mfma_gemm<0><<<ggrid, 256, 0, stream>>>(XNB, GW12, MGAT, 512, 4096, B12,
                                            nullptr, nullptr, nullptr, nullptr, CG);
    gat_attn<<<BG, 256, 0, stream>>>(CG, gat1_att, gat1_bias, bn3_g, bn3_b, Z1B);
    // ---- GAT layer 2 ----
    mfma_gemm<0><<<ggrid, 256, 0, stream>>>(Z1B, GW34, MGAT, 512, 4096, B34,
                                            nullptr, nullptr, nullptr, nullptr, CG);
    gat_attn<<<BG, 256, 0, stream>>>(CG, gat2_att, gat2_bias, bn4_g, bn4_b, Z2B);
    // ---- final fc ----
    final_fc<<<BG / 4, 256, 0, stream>>>(Z2B, fc_W, fc_b, out);
}

// Round 7
// 1034.444 us; speedup vs baseline: 3.5577x; 1.0165x over previous
//
#include <hip/hip_runtime.h>
#include <hip/hip_bf16.h>

#define N_NODESC 100000
#define N_EDGESC 200000
#define BG 2048
#define NDIM 64
#define EDIM 16

typedef __bf16 bf16x8 __attribute__((ext_vector_type(8)));
typedef float f32x4 __attribute__((ext_vector_type(4)));

static __device__ __forceinline__ float bn_inv() { return 0.9999950000374997f; }

// async global->LDS 16B per lane; LDS dest = wave-uniform base + lane*16
__device__ __forceinline__ void gl2lds16(const void* g, void* l) {
    __builtin_amdgcn_global_load_lds(
        (const __attribute__((address_space(1))) unsigned int*)g,
        (__attribute__((address_space(3))) unsigned int*)l, 16, 0, 0);
}

// ---------------- zero fills --------------------------------------------------
__global__ void zero_f4(float4* __restrict__ p, int n4) {
    int i = blockIdx.x * 256 + threadIdx.x;
    if (i < n4) p[i] = make_float4(0.f, 0.f, 0.f, 0.f);
}
__global__ void zero_int(int* __restrict__ p, int n) {
    int i = blockIdx.x * 256 + threadIdx.x;
    if (i < n) p[i] = 0;
}
__global__ void zero_out(float* __restrict__ p, int n) {
    int i = blockIdx.x * 256 + threadIdx.x;
    if (i < n) p[i] = 0.f;
}

// ---------------- CSR build: histogram -> scan -> scatter --------------------
__global__ void hist_dst(const int* __restrict__ dst, int* __restrict__ deg) {
    int i = blockIdx.x * 256 + threadIdx.x;
    if (i < N_EDGESC) atomicAdd(&deg[dst[i]], 1);
}
__global__ void scan_bsums(const int* __restrict__ deg, int* __restrict__ bsum, int n) {
    __shared__ int ls[256];
    int b = blockIdx.x, t = threadIdx.x;
    int s = 0;
#pragma unroll
    for (int j = 0; j < 4; j++) {
        int i = b * 1024 + t * 4 + j;
        if (i < n) s += deg[i];
    }
    ls[t] = s;
    __syncthreads();
    for (int off = 128; off; off >>= 1) {
        if (t < off) ls[t] += ls[t + off];
        __syncthreads();
    }
    if (t == 0) bsum[b] = ls[0];
}
__global__ void scan_top(int* __restrict__ bsum, int nb, int* __restrict__ total) {
    if (threadIdx.x == 0) {
        int acc = 0;
        for (int i = 0; i < nb; i++) { int v = bsum[i]; bsum[i] = acc; acc += v; }
        *total = acc;
    }
}
__global__ void scan_final(const int* __restrict__ deg, const int* __restrict__ bsum,
                           int* __restrict__ rowptr, int* __restrict__ cursor, int n) {
    __shared__ int ls[256];
    int b = blockIdx.x, t = threadIdx.x;
    int v[4], s = 0;
#pragma unroll
    for (int j = 0; j < 4; j++) {
        int i = b * 1024 + t * 4 + j;
        v[j] = (i < n) ? deg[i] : 0;
        s += v[j];
    }
    ls[t] = s;
    __syncthreads();
    int run = s;
    for (int off = 1; off < 256; off <<= 1) {
        int add = (t >= off) ? ls[t - off] : 0;
        __syncthreads();
        ls[t] += add;
        __syncthreads();
    }
    int excl = ls[t] - run + bsum[b];
#pragma unroll
    for (int j = 0; j < 4; j++) {
        int i = b * 1024 + t * 4 + j;
        if (i < n) { rowptr[i] = excl; cursor[i] = excl; excl += v[j]; }
    }
}
__global__ void scatter_eid(const int* __restrict__ dst, int* __restrict__ cursor,
                            int* __restrict__ eid) {
    int e = blockIdx.x * 256 + threadIdx.x;
    if (e < N_EDGESC) {
        int p = atomicAdd(&cursor[dst[e]], 1);
        eid[p] = e;
    }
}

// ---------------- W [K][N] f32 -> bf16 [N][K] --------------------------------
__global__ void transpose_w(const float* __restrict__ W, __hip_bfloat16* __restrict__ hi,
                            int K, int N) {
    __shared__ float t[64][65];
    int k0 = blockIdx.x * 64, n0 = blockIdx.y * 64;
    int tid = threadIdx.x, tx = tid & 63, ty = tid >> 6;
    for (int r = ty; r < 64; r += 4) t[r][tx] = W[(size_t)(k0 + r) * N + n0 + tx];
    __syncthreads();
    for (int r = ty; r < 64; r += 4)
        hi[(size_t)(n0 + r) * K + k0 + tx] = __float2bfloat16(t[tx][r]);
}

__global__ void concat_bias(const float* __restrict__ a, const float* __restrict__ b,
                            float* __restrict__ o) {
    int i = blockIdx.x * 256 + threadIdx.x;
    if (i < 2048) { o[i] = a[i]; o[2048 + i] = b[i]; }
}

// ---------------- GINE1 gather -----------------------------------------------
#define G1_NPW 8
__global__ __launch_bounds__(256, 2) void gine1_gather(
    const float* __restrict__ x, const int* __restrict__ srcv, const float* __restrict__ ea,
    const float* __restrict__ e1W, const float* __restrict__ e1b,
    const int* __restrict__ rowptr, const int* __restrict__ eid,
    __hip_bfloat16* __restrict__ xin) {
    int tid = threadIdx.x;
    int wave = tid >> 6, lane = tid & 63;
    float wreg[16];
#pragma unroll
    for (int k = 0; k < 16; k++) wreg[k] = e1W[k * 64 + lane];
    float bb = e1b[lane];
    int nbase = (blockIdx.x * 4 + wave) * G1_NPW;
#pragma unroll 1
    for (int it = 0; it < G1_NPW; it++) {
        int n = nbase + it;
        if (n >= N_NODESC) return;
        float acc = x[(size_t)n * 64 + lane];
        int beg = rowptr[n], end = rowptr[n + 1];
        for (int idx = beg; idx < end; idx++) {
            int e = eid[idx], s = srcv[e];
            const float4* ef = (const float4*)(ea + (size_t)e * 16);
            float4 e0 = ef[0], e1 = ef[1], e2 = ef[2], e3 = ef[3];
            float p = bb;
            p = fmaf(e0.x, wreg[0], p);  p = fmaf(e0.y, wreg[1], p);
            p = fmaf(e0.z, wreg[2], p);  p = fmaf(e0.w, wreg[3], p);
            p = fmaf(e1.x, wreg[4], p);  p = fmaf(e1.y, wreg[5], p);
            p = fmaf(e1.z, wreg[6], p);  p = fmaf(e1.w, wreg[7], p);
            p = fmaf(e2.x, wreg[8], p);  p = fmaf(e2.y, wreg[9], p);
            p = fmaf(e2.z, wreg[10], p); p = fmaf(e2.w, wreg[11], p);
            p = fmaf(e3.x, wreg[12], p); p = fmaf(e3.y, wreg[13], p);
            p = fmaf(e3.z, wreg[14], p); p = fmaf(e3.w, wreg[15], p);
            acc += fmaxf(x[(size_t)s * 64 + lane] + p, 0.f);
        }
        xin[(size_t)n * 64 + lane] = __float2bfloat16(acc);
    }
}

// ---------------- GINE2 gather -----------------------------------------------
#define G2_NPB 16
__global__ __launch_bounds__(256, 2) void gine2_gather(
    const __hip_bfloat16* __restrict__ h, const int* __restrict__ srcv,
    const float* __restrict__ ea, const float* __restrict__ e2W,
    const float* __restrict__ e2b, const int* __restrict__ rowptr,
    const int* __restrict__ eid, __hip_bfloat16* __restrict__ a2, int n0, int n1) {
    int tid = threadIdx.x;
    int half = tid >> 7, lt = tid & 127;
    float wreg[4][16], breg[4];
#pragma unroll
    for (int j = 0; j < 4; j++) {
        int c = lt * 4 + j;
        breg[j] = e2b[c];
#pragma unroll
        for (int k = 0; k < 16; k++) wreg[j][k] = e2W[k * 512 + c];
    }
    int nbase = n0 + blockIdx.x * G2_NPB + half;
#pragma unroll 1
    for (int it = 0; it < G2_NPB / 2; it++) {
        int n = nbase + it * 2;
        if (n >= n1) return;
        short4 hv = *(const short4*)((const short*)(h + (size_t)n * 512) + lt * 4);
        const __hip_bfloat16* hb = (const __hip_bfloat16*)&hv;
        float acc[4];
#pragma unroll
        for (int j = 0; j < 4; j++) acc[j] = __bfloat162float(hb[j]);
        int beg = rowptr[n], end = rowptr[n + 1];
        for (int idx = beg; idx < end; idx++) {
            int e = eid[idx], s = srcv[e];
            const float4* ef = (const float4*)(ea + (size_t)e * 16);
            float4 e0 = ef[0], e1 = ef[1], e2v = ef[2], e3 = ef[3];
            short4 sv = *(const short4*)((const short*)(h + (size_t)s * 512) + lt * 4);
            const __hip_bfloat16* sb = (const __hip_bfloat16*)&sv;
#pragma unroll
            for (int j = 0; j < 4; j++) {
                float p = breg[j];
                p = fmaf(e0.x, wreg[j][0], p);  p = fmaf(e0.y, wreg[j][1], p);
                p = fmaf(e0.z, wreg[j][2], p);  p = fmaf(e0.w, wreg[j][3], p);
                p = fmaf(e1.x, wreg[j][4], p);  p = fmaf(e1.y, wreg[j][5], p);
                p = fmaf(e1.z, wreg[j][6], p);  p = fmaf(e1.w, wreg[j][7], p);
                p = fmaf(e2v.x, wreg[j][8], p); p = fmaf(e2v.y, wreg[j][9], p);
                p = fmaf(e2v.z, wreg[j][10], p);p = fmaf(e2v.w, wreg[j][11], p);
                p = fmaf(e3.x, wreg[j][12], p); p = fmaf(e3.y, wreg[j][13], p);
                p = fmaf(e3.z, wreg[j][14], p); p = fmaf(e3.w, wreg[j][15], p);
                acc[j] += fmaxf(__bfloat162float(sb[j]) + p, 0.f);
            }
        }
        __hip_bfloat16 o[4];
#pragma unroll
        for (int j = 0; j < 4; j++) o[j] = __float2bfloat16(acc[j]);
        *(short4*)((short*)(a2 + (size_t)(n - n0) * 512) + lt * 4) = *(const short4*)o;
    }
}

// ---------------- MFMA GEMM: C[M,N] = A[M,K](bf16) @ B^T[N,K](bf16) ----------
// m97 structure: unpadded LDS (stride 32), async global_load_lds 16B staging.
// GRID: x = col-tile (fast), y = row-tile.
template <int MODE>
__global__ __launch_bounds__(256, 4) void mfma_gemm(
    const __hip_bfloat16* __restrict__ A, const __hip_bfloat16* __restrict__ Bhi,
    int M, int K, int N, const float* __restrict__ bias, const float* __restrict__ bng,
    const float* __restrict__ bnb, const int* __restrict__ batch,
    float* __restrict__ psum, __hip_bfloat16* __restrict__ Cout) {
    __shared__ short As[128 * 32];   // 8 KB, row-major [128][32], contiguous
    __shared__ short Bh[128 * 32];
    int r0 = blockIdx.y * 128;
    int n0 = blockIdx.x * 128;
    int tid = threadIdx.x;
    int lane = tid & 63;
    int wv = tid >> 6;
    int wm = (wv >> 1) * 64, wn = (wv & 1) * 64;

    f32x4 acc[4][4];
#pragma unroll
    for (int i = 0; i < 4; i++)
#pragma unroll
        for (int j = 0; j < 4; j++) acc[i][j] = (f32x4){0.f, 0.f, 0.f, 0.f};

    // staging indices: linear i in [0,512), row = i>>2, kb = i&3; LDS offset = i*16B
    int rowA0 = tid >> 2, cbA0 = tid & 3;
    int rowA1 = (tid + 256) >> 2, cbA1 = tid & 3;  // (tid+256)&3 == tid&3
    for (int k0 = 0; k0 < K; k0 += 32) {
        __syncthreads();
        {
            int g0 = r0 + rowA0; if (g0 >= M) g0 = M - 1;
            int g1 = r0 + rowA1; if (g1 >= M) g1 = M - 1;
            gl2lds16(A + (size_t)g0 * K + k0 + cbA0 * 8, As + wv * 512);
            gl2lds16(A + (size_t)g1 * K + k0 + cbA1 * 8, As + 2048 + wv * 512);
            gl2lds16(Bhi + (size_t)(n0 + rowA0) * K + k0 + cbA0 * 8, Bh + wv * 512);
            gl2lds16(Bhi + (size_t)(n0 + rowA1) * K + k0 + cbA1 * 8, Bh + 2048 + wv * 512);
        }
        __syncthreads();
        int fi = lane & 15, kb = (lane >> 4) * 8;
        bf16x8 af[4], bhf[4];
#pragma unroll
        for (int mi = 0; mi < 4; mi++)
            af[mi] = *(const bf16x8*)(As + (wm + mi * 16 + fi) * 32 + kb);
#pragma unroll
        for (int ni = 0; ni < 4; ni++)
            bhf[ni] = *(const bf16x8*)(Bh + (wn + ni * 16 + fi) * 32 + kb);
#pragma unroll
        for (int mi = 0; mi < 4; mi++)
#pragma unroll
            for (int ni = 0; ni < 4; ni++)
                acc[mi][ni] = __builtin_amdgcn_mfma_f32_16x16x32_bf16(af[mi], bhf[ni],
                                                                     acc[mi][ni], 0, 0, 0);
    }
    int col_l = lane & 15, quad = lane >> 4;
#pragma unroll
    for (int mi = 0; mi < 4; mi++) {
        int rbase = r0 + wm + mi * 16 + quad * 4;
#pragma unroll
        for (int ni = 0; ni < 4; ni++) {
            int gcol = n0 + wn + ni * 16 + col_l;
            if (MODE == 0) {
                float b0 = bias[gcol];
#pragma unroll
                for (int reg = 0; reg < 4; reg++) {
                    int grow = rbase + reg;
                    if (grow < M)
                        Cout[(size_t)grow * N + gcol] = __float2bfloat16(acc[mi][ni][reg] + b0);
                }
            } else {
                float b0 = bias[gcol], g0 = bng[gcol], bb0 = bnb[gcol];
                float vv[4];
#pragma unroll
                for (int reg = 0; reg < 4; reg++)
                    vv[reg] = fmaxf(fmaf((acc[mi][ni][reg] + b0) * bn_inv(), g0, bb0), 0.f);
                if (MODE == 1) {
#pragma unroll
                    for (int reg = 0; reg < 4; reg++) {
                        int grow = rbase + reg;
                        if (grow < M) Cout[(size_t)grow * 512 + gcol] = __float2bfloat16(vv[reg]);
                    }
                } else {
                    if (rbase + 3 < M && batch[rbase] == batch[rbase + 3]) {
                        atomicAdd(&psum[(size_t)batch[rbase] * 512 + gcol],
                                  (vv[0] + vv[1]) + (vv[2] + vv[3]));
                    } else {
#pragma unroll
                        for (int reg = 0; reg < 4; reg++) {
                            int grow = rbase + reg;
                            if (grow < M)
                                atomicAdd(&psum[(size_t)batch[grow] * 512 + gcol], vv[reg]);
                        }
                    }
                }
            }
        }
    }
}

// ---------------- node counts per graph --------------------------------------
__global__ void count_nodes(const int* __restrict__ batch, float* __restrict__ cnt) {
    int i = blockIdx.x * 256 + threadIdx.x;
    if (i < N_NODESC) atomicAdd(&cnt[batch[i]], 1.0f);
}

// ---------------- finalize pool + assemble xn [B,7,512] bf16 -----------------
__global__ void build_xn(const float* __restrict__ psum, const float* __restrict__ cnt,
                         const float* __restrict__ ecfp, const float* __restrict__ topo,
                         const float* __restrict__ maccs, const float* __restrict__ estate,
                         const float* __restrict__ rdkit2d, const float* __restrict__ phar2d,
                         __hip_bfloat16* __restrict__ xn) {
    int i = blockIdx.x * 256 + threadIdx.x;
    if (i >= BG * 512) return;
    int bidx = i >> 9, c = i & 511;
    float cv = fmaxf(cnt[bidx], 1.0f);
    __hip_bfloat16* o = xn + (size_t)bidx * 7 * 512;
    o[c] = __float2bfloat16(psum[i] / cv);
    o[512 + c] = __float2bfloat16(ecfp[i]);
    o[2 * 512 + c] = __float2bfloat16(topo[i]);
    o[3 * 512 + c] = __float2bfloat16(maccs[i]);
    o[4 * 512 + c] = __float2bfloat16(estate[i]);
    o[5 * 512 + c] = __float2bfloat16(rdkit2d[i]);
    o[6 * 512 + c] = __float2bfloat16(phar2d[i]);
}

// ---------------- GAT attention (fused gl|gr layout: C[B*7][4096]) -----------
__global__ void gat_attn(const __hip_bfloat16* __restrict__ cg,
                         const float* __restrict__ att, const float* __restrict__ bias,
                         const float* __restrict__ bng, const float* __restrict__ bnb,
                         __hip_bfloat16* __restrict__ zout) {
    int b = blockIdx.x;
    int tid = threadIdx.x;
    int wave = tid >> 6, lane = tid & 63;
    __shared__ float logits[13][4];
    __shared__ float alpha[13][4];
    const size_t base = (size_t)b * 7 * 4096;
    for (int p = wave; p < 52; p += 4) {
        int e = p >> 2, hh = p & 3;
        int se = (e < 7) ? 0 : (e - 6);
        int de = (e < 6) ? (e + 1) : ((e == 6) ? 0 : (e - 6));
        const __hip_bfloat16* glp = cg + base + (size_t)se * 4096 + hh * 512;
        const __hip_bfloat16* grp = cg + base + (size_t)de * 4096 + 2048 + hh * 512;
        const float* ap = att + hh * 512;
        float s = 0.f;
#pragma unroll
        for (int j = 0; j < 8; j++) {
            int c = lane + j * 64;
            float v = __bfloat162float(glp[c]) + __bfloat162float(grp[c]);
            v = (v >= 0.f) ? v : 0.2f * v;
            s = fmaf(v, ap[c], s);
        }
#pragma unroll
        for (int off = 32; off; off >>= 1) s += __shfl_down(s, off);
        if (lane == 0) logits[e][hh] = s;
    }
    __syncthreads();
    if (tid < 24) {
        int n = 1 + (tid >> 2), hh = tid & 3;
        float la = logits[n - 1][hh], lb = logits[6 + n][hh];
        float m = fmaxf(la, lb);
        float ea = __expf(la - m), eb = __expf(lb - m);
        float inv = 1.f / (ea + eb);
        alpha[n - 1][hh] = ea * inv;
        alpha[6 + n][hh] = eb * inv;
    } else if (tid < 28) {
        alpha[6][tid & 3] = 1.f;
    }
    __syncthreads();
    for (int i = tid; i < 7 * 512; i += 256) {
        int n = i >> 9, c = i & 511;
        float v = 0.f;
        if (n == 0) {
#pragma unroll
            for (int hh = 0; hh < 4; hh++)
                v = fmaf(alpha[6][hh],
                         __bfloat162float(cg[base + (size_t)hh * 512 + c]), v);
        } else {
#pragma unroll
            for (int hh = 0; hh < 4; hh++) {
                v = fmaf(alpha[n - 1][hh],
                         __bfloat162float(cg[base + (size_t)hh * 512 + c]), v);
                v = fmaf(alpha[6 + n][hh],
                         __bfloat162float(cg[base + (size_t)n * 4096 + hh * 512 + c]), v);
            }
        }
        v = fmaf(v, 0.25f, bias[c]);
        v = fmaf(v * bn_inv(), bng[c], bnb[c]);
        zout[(size_t)b * 7 * 512 + i] = __float2bfloat16(fmaxf(v, 0.f));
    }
}

// ---------------- final fc ----------------------------------------------------
__global__ void final_fc(const __hip_bfloat16* __restrict__ z, const float* __restrict__ fcW,
                         const float* __restrict__ fcb, float* __restrict__ out) {
    int b = blockIdx.x * 4 + (threadIdx.x >> 6);
    int lane = threadIdx.x & 63;
    if (b >= BG) return;
    const __hip_bfloat16* row = z + (size_t)b * 7 * 512;
    float s = 0.f;
#pragma unroll
    for (int j = 0; j < 8; j++)
        s = fmaf(__bfloat162float(row[lane + j * 64]), fcW[lane + j * 64], s);
#pragma unroll
    for (int off = 32; off; off >>= 1) s += __shfl_down(s, off);
    if (lane == 0) out[b] = s + fcb[0];
}

extern "C" void kernel_launch(void* const* d_in, const int* in_sizes, int n_in,
                              void* d_out, int out_size, void* d_ws, size_t ws_size,
                              hipStream_t stream) {
    const float* x = (const float*)d_in[0];
    const int* eidx = (const int*)d_in[1];
    const float* eattr = (const float*)d_in[2];
    const int* batch = (const int*)d_in[3];
    const float* ecfp = (const float*)d_in[4];
    const float* topo = (const float*)d_in[5];
    const float* maccs = (const float*)d_in[6];
    const float* estate = (const float*)d_in[7];
    const float* rdkit2d = (const float*)d_in[8];
    const float* phar2d = (const float*)d_in[9];
    const float* g1_W = (const float*)d_in[10];
    const float* g1_b = (const float*)d_in[11];
    const float* e1_W = (const float*)d_in[12];
    const float* e1_b = (const float*)d_in[13];
    const float* bn1_g = (const float*)d_in[14];
    const float* bn1_b = (const float*)d_in[15];
    const float* g2_W = (const float*)d_in[16];
    const float* g2_b = (const float*)d_in[17];
    const float* e2_W = (const float*)d_in[18];
    const float* e2_b = (const float*)d_in[19];
    const float* bn2_g = (const float*)d_in[20];
    const float* bn2_b = (const float*)d_in[21];
    const float* gat1_Wl = (const float*)d_in[22];
    const float* gat1_bl = (const float*)d_in[23];
    const float* gat1_Wr = (const float*)d_in[24];
    const float* gat1_br = (const float*)d_in[25];
    const float* gat1_att = (const float*)d_in[26];
    const float* gat1_bias = (const float*)d_in[27];
    const float* bn3_g = (const float*)d_in[28];
    const float* bn3_b = (const float*)d_in[29];
    const float* gat2_Wl = (const float*)d_in[30];
    const float* gat2_bl = (const float*)d_in[31];
    const float* gat2_Wr = (const float*)d_in[32];
    const float* gat2_br = (const float*)d_in[33];
    const float* gat2_att = (const float*)d_in[34];
    const float* gat2_bias = (const float*)d_in[35];
    const float* bn4_g = (const float*)d_in[36];
    const float* bn4_b = (const float*)d_in[37];
    const float* fc_W = (const float*)d_in[38];
    const float* fc_b = (const float*)d_in[39];
    float* out = (float*)d_out;

    const size_t NEEDED = 194682880ull;
    if (ws_size < NEEDED) {
        zero_out<<<(BG + 255) / 256, 256, 0, stream>>>(out, BG);
        return;
    }
    char* w = (char*)d_ws;
    __hip_bfloat16* H = (__hip_bfloat16*)w;
    __hip_bfloat16* CG = (__hip_bfloat16*)w;
    __hip_bfloat16* A2 = (__hip_bfloat16*)(w + 102400000);
    __hip_bfloat16* GW12 = (__hip_bfloat16*)(w + 117440512);
    __hip_bfloat16* GW34 = (__hip_bfloat16*)(w + 121634816);
    __hip_bfloat16* Z1B = (__hip_bfloat16*)(w + 125829120);
    float* B12 = (float*)(w + 140509184);
    float* B34 = (float*)(w + 140525568);

    char* C = w + 161120256;
    __hip_bfloat16* XIN = (__hip_bfloat16*)C;
    __hip_bfloat16* XNB = (__hip_bfloat16*)C;
    __hip_bfloat16* Z2B = (__hip_bfloat16*)(C + 14680064);
    int* ROWPTR = (int*)(C + 14680064);
    int* CURSOR = (int*)(C + 15080192);
    int* EID = (int*)(C + 15480320);
    int* DEG = (int*)(C + 16280320);
    __hip_bfloat16* G1W = (__hip_bfloat16*)(C + 16680320);
    __hip_bfloat16* G2W = (__hip_bfloat16*)(C + 16745856);
    int* BSUM = (int*)(C + 17270144);

    float* PS = (float*)(w + 190480384);
    float* PC = (float*)(w + 194674688);

    const int* src = eidx;
    const int* dst = eidx + N_EDGESC;

    // ---- CSR build ----
    zero_int<<<(N_NODESC + 255) / 256, 256, 0, stream>>>(DEG, N_NODESC);
    zero_f4<<<(BG * 512 / 4 + 255) / 256, 256, 0, stream>>>((float4*)PS, BG * 512 / 4);
    zero_f4<<<(BG / 4 + 255) / 256, 256, 0, stream>>>((float4*)PC, BG / 4);
    hist_dst<<<(N_EDGESC + 255) / 256, 256, 0, stream>>>(dst, DEG);
    const int NB = (N_NODESC + 1023) / 1024;  // 98
    scan_bsums<<<NB, 256, 0, stream>>>(DEG, BSUM, N_NODESC);
    scan_top<<<1, 64, 0, stream>>>(BSUM, NB, ROWPTR + N_NODESC);
    scan_final<<<NB, 256, 0, stream>>>(DEG, BSUM, ROWPTR, CURSOR, N_NODESC);
    scatter_eid<<<(N_EDGESC + 255) / 256, 256, 0, stream>>>(dst, CURSOR, EID);

    // ---- GINE weight prep ----
    transpose_w<<<dim3(1, 8), 256, 0, stream>>>(g1_W, G1W, 64, 512);
    transpose_w<<<dim3(8, 8), 256, 0, stream>>>(g2_W, G2W, 512, 512);

    // ---- GINE1 ----
    gine1_gather<<<(N_NODESC + 4 * G1_NPW - 1) / (4 * G1_NPW), 256, 0, stream>>>(
        x, src, eattr, e1_W, e1_b, ROWPTR, EID, XIN);
    mfma_gemm<1><<<dim3(4, (N_NODESC + 127) / 128), 256, 0, stream>>>(
        XIN, G1W, N_NODESC, 64, 512, g1_b, bn1_g, bn1_b, nullptr, nullptr, H);
    count_nodes<<<(N_NODESC + 255) / 256, 256, 0, stream>>>(batch, PC);

    // ---- GINE2: 2 chunks of 50k nodes ----
    for (int c0n = 0; c0n < N_NODESC; c0n += 50000) {
        int c1n = c0n + 50000;
        int rows = 50000;
        gine2_gather<<<(rows + G2_NPB - 1) / G2_NPB, 256, 0, stream>>>(
            H, src, eattr, e2_W, e2_b, ROWPTR, EID, A2, c0n, c1n);
        mfma_gemm<2><<<dim3(4, (rows + 127) / 128), 256, 0, stream>>>(
            A2, G2W, rows, 512, 512, g2_b, bn2_g, bn2_b, batch + c0n, PS, nullptr);
    }

    // ---- GAT weight prep (H and A2 dead) ----
    transpose_w<<<dim3(8, 32), 256, 0, stream>>>(gat1_Wl, GW12, 512, 2048);
    transpose_w<<<dim3(8, 32), 256, 0, stream>>>(gat1_Wr, GW12 + (size_t)2048 * 512, 512, 2048);
    transpose_w<<<dim3(8, 32), 256, 0, stream>>>(gat2_Wl, GW34, 512, 2048);
    transpose_w<<<dim3(8, 32), 256, 0, stream>>>(gat2_Wr, GW34 + (size_t)2048 * 512, 512, 2048);
    concat_bias<<<8, 256, 0, stream>>>(gat1_bl, gat1_br, B12);
    concat_bias<<<8, 256, 0, stream>>>(gat2_bl, gat2_br, B34);

    // ---- pool -> xn ----
    build_xn<<<(BG * 512) / 256, 256, 0, stream>>>(PS, PC, ecfp, topo, maccs, estate,
                                                   rdkit2d, phar2d, XNB);
    // ---- GAT layer 1 (fused L|R: N = 4096) ----
    const int MGAT = BG * 7;  // 14336
    dim3 ggrid(4096 / 128, MGAT / 128);
    mfma_gemm<0><<<ggrid, 256, 0, stream>>>(XNB, GW12, MGAT, 512, 4096, B12,
                                            nullptr, nullptr, nullptr, nullptr, CG);
    gat_attn<<<BG, 256, 0, stream>>>(CG, gat1_att, gat1_bias, bn3_g, bn3_b, Z1B);
    // ---- GAT layer 2 ----
    mfma_gemm<0><<<ggrid, 256, 0, stream>>>(Z1B, GW34, MGAT, 512, 4096, B34,
                                            nullptr, nullptr, nullptr, nullptr, CG);
    gat_attn<<<BG, 256, 0, stream>>>(CG, gat2_att, gat2_bias, bn4_g, bn4_b, Z2B);
    // ---- final fc ----
    final_fc<<<BG / 4, 256, 0, stream>>>(Z2B, fc_W, fc_b, out);
}